// Round 15
// baseline (337.044 us; speedup 1.0000x reference)
//
#include <hip/hip_runtime.h>
#include <hip/hip_fp16.h>
#include <cstdint>
#include <cstddef>

#define NNODES 100000
#define NEDGES 1600000
#define NGRAPHS 64
#define BSHIFT 7
#define BRANGE 128
#define NB 782   // ceil(NNODES / 128)
#define CAP 4096 // edges per bucket frame (mean 2046, sd 45 -> >40 sigma headroom)
#define NZ NB    // ints to zero (bcur)
#define LP 136   // LDS row pitch in shorts (272B: 16B-aligned, 2-way max bank alias)
#define NAB 25000 // agg2 blocks (N/4)

typedef short short8v __attribute__((ext_vector_type(8)));
typedef float float4v __attribute__((ext_vector_type(4)));

__device__ inline short f2h_s(float f) {
    __half h = __float2half(f);
    return __builtin_bit_cast(short, h);
}
__device__ inline ushort f2h_u(float f) {
    __half h = __float2half(f);
    return __builtin_bit_cast(ushort, h);
}
__device__ inline __half2 u2h2(uint u) { return __builtin_bit_cast(__half2, u); }
__device__ inline uint h22u(__half2 h) { return __builtin_bit_cast(uint, h); }

// ---------------- setup: zero ∪ prepw ∪ bounds (block-range partitioned) ----------------

__global__ __launch_bounds__(256) void k_setup(int* __restrict__ zb,
                                               const float* __restrict__ W1,
                                               const float* __restrict__ W2,
                                               short8v* __restrict__ o1,
                                               short8v* __restrict__ o2,
                                               const int* __restrict__ batch,
                                               int* __restrict__ gstart,
                                               int* __restrict__ gend) {
    int b = blockIdx.x, t = threadIdx.x;
    if (b < 4) {
        int i = b * 256 + t;
        if (i < NZ) zb[i] = 0;
    } else if (b < 6) {
        const float* W = (b == 5) ? W2 : W1;
        short8v* o = (b == 5) ? o2 : o1;
        for (int s = t; s < 2048; s += 256) {
            int p = s >> 6, l = s & 63;
            int kb = (p >> 3) * 32 + ((l >> 4) * 8);
            int j = (p & 7) * 16 + (l & 15);
            short8v v;
            #pragma unroll
            for (int i = 0; i < 8; ++i)
                v[i] = f2h_s(W[(size_t)(kb + i) * 128 + j]);
            o[s] = v;
        }
    } else {
        int i = (b - 6) * 256 + t;
        if (i < NNODES) {
            int bb = batch[i];
            if (i == 0 || batch[i - 1] != bb) gstart[bb] = i;
            if (i == NNODES - 1 || batch[i + 1] != bb) gend[bb] = i + 1;
        }
    }
}

// ---------------- P1: bucket scatter with direct atomic reservation ----------------

#define P1_EPT 8
__global__ __launch_bounds__(256) void k_bscatter(const int* __restrict__ src,
                                                  const int* __restrict__ dst,
                                                  int* __restrict__ bcur,
                                                  uint* __restrict__ pairs, int E) {
    __shared__ int h[NB];
    __shared__ int base[NB];
    int t = threadIdx.x;
    long long c0 = (long long)blockIdx.x * 2048;
    if (c0 >= E) return;
    for (int i = t; i < NB; i += 256) h[i] = 0;
    __syncthreads();
    int myb[P1_EPT], mylp[P1_EPT];
    uint myv[P1_EPT];
    #pragma unroll
    for (int k = 0; k < P1_EPT; ++k) {
        long long e = c0 + t + k * 256;
        if (e < E) {
            int d = dst[e];
            myv[k] = (uint)src[e] | ((uint)(d & (BRANGE - 1)) << 24);
            myb[k] = d >> BSHIFT;
            mylp[k] = atomicAdd(&h[myb[k]], 1);
        } else myb[k] = -1;
    }
    __syncthreads();
    for (int i = t; i < NB; i += 256)
        base[i] = h[i] ? atomicAdd(&bcur[i], h[i]) : 0;
    __syncthreads();
    #pragma unroll
    for (int k = 0; k < P1_EPT; ++k)
        if (myb[k] >= 0) {
            int pos = base[myb[k]] + mylp[k];
            if (pos < CAP)
                pairs[(size_t)myb[k] * CAP + pos] = myv[k];
        }
}

// ---------------- fused per-bucket: histogram -> dinv + node ranges -> CSR scatter ----------------

__global__ __launch_bounds__(256) void k_build(const uint* __restrict__ pairs,
                                               const int* __restrict__ bcur,
                                               int2* __restrict__ nr,
                                               float* __restrict__ dinv,
                                               int* __restrict__ csr, int N) {
    __shared__ int h[256];
    __shared__ int sh[256];
    __shared__ int cur[BRANGE];
    int b = blockIdx.x, t = threadIdx.x;
    h[t] = 0;
    __syncthreads();
    const int p0 = b * CAP;
    const int cntb = min(bcur[b], CAP);
    for (int p = t; p < cntb; p += 256)
        atomicAdd(&h[pairs[p0 + p] >> 24], 1);
    __syncthreads();
    int myh = h[t];
    sh[t] = myh;
    __syncthreads();
    #pragma unroll
    for (int d = 1; d < 256; d <<= 1) {
        int val = (t >= d) ? sh[t - d] : 0;
        __syncthreads();
        sh[t] += val;
        __syncthreads();
    }
    int excl = sh[t] - myh;
    int node = (b << BSHIFT) + t;
    if (t < BRANGE) {
        cur[t] = p0 + excl;
        if (node < N) {
            nr[node] = make_int2(p0 + excl, p0 + excl + myh);
            dinv[node] = rsqrtf((float)(myh + 1));
        }
    }
    __syncthreads();
    for (int p = t; p < cntb; p += 256) {
        uint pr = pairs[p0 + p];
        int pos = atomicAdd(&cur[pr >> 24], 1);
        csr[pos] = (int)(pr & 0x00FFFFFFu);
    }
}

// ---------------- GEMM1 (f32 in): msg1[n,128] = (X @ W1) * dinv[row], fp16 out ----------------

__global__ __launch_bounds__(256) void k_gemm_f32(const float* __restrict__ X,
                                                  const short8v* __restrict__ wf,
                                                  const float* __restrict__ dinv,
                                                  ushort* __restrict__ Y, int nrows) {
    __shared__ short8v sW[2048];
    const int tid = threadIdx.x;
    const int lane = tid & 63;
    const int w = tid >> 6;

    for (int s = tid; s < 2048; s += 256) sW[s] = wf[s];
    __syncthreads();

    const int row0 = blockIdx.x * 64 + w * 16;
    const int arow = row0 + (lane & 15);
    float4v acc[8];
    #pragma unroll
    for (int ct = 0; ct < 8; ++ct) acc[ct] = (float4v)0.f;

    #pragma unroll
    for (int kk = 0; kk < 4; ++kk) {
        short8v a = (short8v)0;
        if (arow < nrows) {
            const float* xp = X + (size_t)arow * 128 + kk * 32 + ((lane >> 4) * 8);
            float4 f0 = ((const float4*)xp)[0];
            float4 f1 = ((const float4*)xp)[1];
            a[0] = f2h_s(f0.x); a[1] = f2h_s(f0.y);
            a[2] = f2h_s(f0.z); a[3] = f2h_s(f0.w);
            a[4] = f2h_s(f1.x); a[5] = f2h_s(f1.y);
            a[6] = f2h_s(f1.z); a[7] = f2h_s(f1.w);
        }
        #pragma unroll
        for (int ct = 0; ct < 8; ++ct)
            acc[ct] = __builtin_amdgcn_mfma_f32_16x16x32_f16(a, sW[(kk * 8 + ct) * 64 + lane],
                                                             acc[ct], 0, 0, 0);
    }

    const int orow = row0 + ((lane >> 4) << 2);
    #pragma unroll
    for (int r = 0; r < 4; ++r) {
        int row = orow + r;
        if (row < nrows) {
            float dr = dinv[row];
            #pragma unroll
            for (int ct = 0; ct < 8; ++ct)
                Y[(size_t)row * 128 + ct * 16 + (lane & 15)] = f2h_u(acc[ct][r] * dr);
        }
    }
}

// ---------------- FUSED agg1 + GEMM2 ----------------
// Phase 1: each wave aggregates 16 nodes (6-deep gathers), h1 = relu(dinv*sum + b1) -> LDS.
// Phase 2: 64x128 MFMA tile, A from LDS, W2 fragments from global (L2-hot); msg2 = acc*dinv.

__global__ __launch_bounds__(256, 6) void k_agg_gemm(const uint* __restrict__ msg,
                                                     const float* __restrict__ dinv,
                                                     const int2* __restrict__ nr,
                                                     const int* __restrict__ csr,
                                                     const float* __restrict__ bias,
                                                     const short8v* __restrict__ wf,
                                                     ushort* __restrict__ Y, int n) {
    __shared__ ushort ht[64 * LP];  // 17.4 KB
    const int t = threadIdx.x;
    const int lane = t & 63;
    const int w = t >> 6;
    const int row0 = blockIdx.x * 64;
    const float bx = bias[lane * 2];
    const float by = bias[lane * 2 + 1];

    // phase 1: aggregate 16 nodes per wave
    for (int i = 0; i < 16; ++i) {
        const int r = w * 16 + i;
        const int wid = row0 + r;
        uint o = 0u;
        if (wid < n) {
            __half2 a0 = u2h2(msg[(size_t)wid * 64 + lane]);
            __half2 a1 = u2h2(0u), a2 = u2h2(0u);
            const int2 rg = nr[wid];
            const int e0 = rg.x, e1 = rg.y;
            for (int e = e0; e < e1; e += 64) {
                int me = e + lane;
                int sidx = (me < e1) ? csr[me] : 0;
                int cnt = min(64, e1 - e);
                for (int kb = 0; kb < cnt; kb += 6) {
                    int lim = cnt - 1;
                    int s0 = __shfl(sidx, min(kb + 0, lim));
                    int s1 = __shfl(sidx, min(kb + 1, lim));
                    int s2 = __shfl(sidx, min(kb + 2, lim));
                    int s3 = __shfl(sidx, min(kb + 3, lim));
                    int s4 = __shfl(sidx, min(kb + 4, lim));
                    int s5 = __shfl(sidx, min(kb + 5, lim));
                    uint u0 = msg[(size_t)s0 * 64 + lane];
                    uint u1 = msg[(size_t)s1 * 64 + lane];
                    uint u2 = msg[(size_t)s2 * 64 + lane];
                    uint u3 = msg[(size_t)s3 * 64 + lane];
                    uint u4 = msg[(size_t)s4 * 64 + lane];
                    uint u5 = msg[(size_t)s5 * 64 + lane];
                    u1 = (kb + 1 < cnt) ? u1 : 0u;
                    u2 = (kb + 2 < cnt) ? u2 : 0u;
                    u3 = (kb + 3 < cnt) ? u3 : 0u;
                    u4 = (kb + 4 < cnt) ? u4 : 0u;
                    u5 = (kb + 5 < cnt) ? u5 : 0u;
                    a0 = __hadd2(a0, u2h2(u0));
                    a1 = __hadd2(a1, u2h2(u1));
                    a2 = __hadd2(a2, u2h2(u2));
                    a0 = __hadd2(a0, u2h2(u3));
                    a1 = __hadd2(a1, u2h2(u4));
                    a2 = __hadd2(a2, u2h2(u5));
                }
            }
            __half2 acc = __hadd2(__hadd2(a0, a1), a2);
            float2 f = __half22float2(acc);
            float dd = dinv[wid];
            float ax = fmaxf(f.x * dd + bx, 0.f);
            float ay = fmaxf(f.y * dd + by, 0.f);
            o = h22u(__floats2half2_rn(ax, ay));
        }
        *(uint*)&ht[r * LP + lane * 2] = o;
    }
    __syncthreads();

    // phase 2: GEMM on the 64x128 LDS tile
    float4v acc[8];
    #pragma unroll
    for (int ct = 0; ct < 8; ++ct) acc[ct] = (float4v)0.f;
    const int arow = w * 16 + (lane & 15);
    #pragma unroll 1
    for (int kk = 0; kk < 4; ++kk) {
        short8v a = *(const short8v*)&ht[arow * LP + kk * 32 + ((lane >> 4) * 8)];
        #pragma unroll
        for (int ct = 0; ct < 8; ++ct)
            acc[ct] = __builtin_amdgcn_mfma_f32_16x16x32_f16(a, wf[(kk * 8 + ct) * 64 + lane],
                                                             acc[ct], 0, 0, 0);
    }
    const int orow = row0 + w * 16 + ((lane >> 4) << 2);
    #pragma unroll
    for (int r = 0; r < 4; ++r) {
        int row = orow + r;
        if (row < n) {
            float dr = dinv[row];
            #pragma unroll
            for (int ct = 0; ct < 8; ++ct)
                Y[(size_t)row * 128 + ct * 16 + (lane & 15)] = f2h_u(acc[ct][r] * dr);
        }
    }
}

// ---------------- FUSED agg2 + pool: per-block (4 nodes) partial sums, A/B by graph ----------------

__global__ __launch_bounds__(256) void k_agg_pool(const uint* __restrict__ msg,
                                                  const float* __restrict__ dinv,
                                                  const int2* __restrict__ nr,
                                                  const int* __restrict__ csr,
                                                  const int* __restrict__ batch,
                                                  float* __restrict__ pA,
                                                  float* __restrict__ pB) {
    __shared__ float red[4][128];
    __shared__ int selw[4];
    const int blk = blockIdx.x;
    const int t = threadIdx.x;
    const int lane = t & 63;
    const int w = t >> 6;
    const int wid = blk * 4 + w;  // N % 4 == 0, always valid

    __half2 a0 = u2h2(msg[(size_t)wid * 64 + lane]);
    __half2 a1 = u2h2(0u), a2 = u2h2(0u);
    const int2 rg = nr[wid];
    const int e0 = rg.x, e1 = rg.y;
    for (int e = e0; e < e1; e += 64) {
        int me = e + lane;
        int sidx = (me < e1) ? csr[me] : 0;
        int cnt = min(64, e1 - e);
        for (int kb = 0; kb < cnt; kb += 6) {
            int lim = cnt - 1;
            int s0 = __shfl(sidx, min(kb + 0, lim));
            int s1 = __shfl(sidx, min(kb + 1, lim));
            int s2 = __shfl(sidx, min(kb + 2, lim));
            int s3 = __shfl(sidx, min(kb + 3, lim));
            int s4 = __shfl(sidx, min(kb + 4, lim));
            int s5 = __shfl(sidx, min(kb + 5, lim));
            uint u0 = msg[(size_t)s0 * 64 + lane];
            uint u1 = msg[(size_t)s1 * 64 + lane];
            uint u2 = msg[(size_t)s2 * 64 + lane];
            uint u3 = msg[(size_t)s3 * 64 + lane];
            uint u4 = msg[(size_t)s4 * 64 + lane];
            uint u5 = msg[(size_t)s5 * 64 + lane];
            u1 = (kb + 1 < cnt) ? u1 : 0u;
            u2 = (kb + 2 < cnt) ? u2 : 0u;
            u3 = (kb + 3 < cnt) ? u3 : 0u;
            u4 = (kb + 4 < cnt) ? u4 : 0u;
            u5 = (kb + 5 < cnt) ? u5 : 0u;
            a0 = __hadd2(a0, u2h2(u0));
            a1 = __hadd2(a1, u2h2(u1));
            a2 = __hadd2(a2, u2h2(u2));
            a0 = __hadd2(a0, u2h2(u3));
            a1 = __hadd2(a1, u2h2(u4));
            a2 = __hadd2(a2, u2h2(u5));
        }
    }
    __half2 acc = __hadd2(__hadd2(a0, a1), a2);
    float2 f = __half22float2(acc);
    float dd = dinv[wid];
    // h2 values (no bias/relu in layer 2); accumulate into per-block partials
    red[w][lane * 2] = f.x * dd;
    red[w][lane * 2 + 1] = f.y * dd;
    if (lane == 0) selw[w] = (batch[wid] != batch[blk * 4]) ? 1 : 0;
    __syncthreads();
    if (t < 128) {
        float a = 0.f, b = 0.f;
        #pragma unroll
        for (int ww = 0; ww < 4; ++ww) {
            float v = red[ww][t];
            if (selw[ww]) b += v; else a += v;
        }
        pA[(size_t)blk * 128 + t] = a;
        if (selw[0] | selw[1] | selw[2] | selw[3])
            pB[(size_t)blk * 128 + t] = b;
    }
}

// ---------------- final: per-graph reduce of block partials + linear head ----------------

__global__ __launch_bounds__(128) void k_final(const float* __restrict__ pA,
                                               const float* __restrict__ pB,
                                               const int* __restrict__ batch,
                                               const int* __restrict__ gstart,
                                               const int* __restrict__ gend,
                                               const float* __restrict__ b2,
                                               const float* __restrict__ linW,
                                               const float* __restrict__ linb,
                                               float* __restrict__ out) {
    __shared__ float red[128][8];
    int g = blockIdx.x, t = threadIdx.x;  // t = channel c
    int b0 = gstart[g] >> 2;
    int b1 = (gend[g] - 1) >> 2;
    float v = 0.f;
    for (int b = b0; b <= b1; ++b) {
        const float* p = (batch[b * 4] != g) ? pB : pA;
        v += p[(size_t)b * 128 + t];
    }
    float cnt = (float)(gend[g] - gstart[g]);
    float sv = v / fmaxf(cnt, 1.0f) + b2[t];
    #pragma unroll
    for (int k = 0; k < 8; ++k) red[t][k] = sv * linW[(size_t)t * 8 + k];
    __syncthreads();
    #pragma unroll
    for (int st = 64; st > 0; st >>= 1) {
        if (t < st) {
            #pragma unroll
            for (int k = 0; k < 8; ++k) red[t][k] += red[t + st][k];
        }
        __syncthreads();
    }
    if (t < 8) out[(size_t)g * 8 + t] = red[0][t] + linb[t];
}

// ---------------- launch ----------------

extern "C" void kernel_launch(void* const* d_in, const int* in_sizes, int n_in,
                              void* d_out, int out_size, void* d_ws, size_t ws_size,
                              hipStream_t stream) {
    const float* x     = (const float*)d_in[0];
    const int*   ei    = (const int*)d_in[1];  // [2,E]: src = ei, dst = ei+E
    const int*   batch = (const int*)d_in[2];
    const float* W1    = (const float*)d_in[3];
    const float* b1    = (const float*)d_in[4];
    const float* W2    = (const float*)d_in[5];
    const float* b2    = (const float*)d_in[6];
    const float* linW  = (const float*)d_in[7];
    const float* linb  = (const float*)d_in[8];
    float* out = (float*)d_out;

    const int N = NNODES, E = NEDGES;
    const int* src = ei;
    const int* dst = ei + E;

    char* ws = (char*)d_ws;
    uint*  bufA16 = (uint*)ws;     ws += (size_t)N * 64 * 4;   // msg1 (fp16), 25.6MB
    uint*  bufH16 = (uint*)ws;     ws += (size_t)N * 64 * 4;   // msg2 (fp16), 25.6MB
    float* dinv   = (float*)ws;    ws += (size_t)N * 4;
    int2*  nr     = (int2*)ws;     ws += (size_t)N * 8;        // per-node (start,end)
    int*   csr    = (int*)ws;      ws += (size_t)NB * CAP * 4; // 12.8MB bucket frames
    int*   bcur   = (int*)ws;      ws += NB * 4;               // zero region
    int*   gstart = (int*)ws;      ws += NGRAPHS * 4;
    int*   gend   = (int*)ws;      ws += NGRAPHS * 4;
    short8v* wf1  = (short8v*)ws;  ws += 2048 * 16;            // fragment-ordered W1 (32KB)
    short8v* wf2  = (short8v*)ws;  ws += 2048 * 16;            // fragment-ordered W2 (32KB)
    float* pA     = (float*)ws;    ws += (size_t)NAB * 128 * 4;  // 12.8MB
    float* pB     = (float*)ws;    ws += (size_t)NAB * 128 * 4;  // 12.8MB
    // pairs aliases bufH16 (12.8MB < 25.6MB): CSR build completes before msg2 written
    uint*  pairs  = (uint*)bufH16;

    const int B = 256;

    // setup: zero(4) + prepw(2) + bounds(391) = 397 blocks
    k_setup<<<397, B, 0, stream>>>(bcur, W1, W2, wf1, wf2, batch, gstart, gend);

    // CSR build
    k_bscatter<<<(E + 2047) / 2048, B, 0, stream>>>(src, dst, bcur, pairs, E);
    k_build<<<NB, B, 0, stream>>>(pairs, bcur, nr, dinv, csr, N);

    const int gemmGrid = (N + 63) / 64;

    // layer 1 GEMM: msg1 = (x @ W1) * dinv
    k_gemm_f32<<<gemmGrid, B, 0, stream>>>(x, wf1, dinv, (ushort*)bufA16, N);

    // fused agg1 + GEMM2: msg2 = (relu(agg(msg1)+b1) @ W2) * dinv
    k_agg_gemm<<<gemmGrid, B, 0, stream>>>(bufA16, dinv, nr, csr, b1, wf2,
                                           (ushort*)bufH16, N);

    // fused agg2 + pool: per-block partial sums of h2
    k_agg_pool<<<NAB, B, 0, stream>>>(bufH16, dinv, nr, csr, batch, pA, pB);

    // per-graph reduce + head
    k_final<<<NGRAPHS, 128, 0, stream>>>(pA, pB, batch, gstart, gend, b2, linW, linb, out);
}

// Round 16
// 215.633 us; speedup vs baseline: 1.5630x; 1.5630x over previous
//
#include <hip/hip_runtime.h>
#include <hip/hip_fp16.h>
#include <cstdint>
#include <cstddef>

#define NNODES 100000
#define NEDGES 1600000
#define NGRAPHS 64
#define BSHIFT 7
#define BRANGE 128
#define NB 782   // ceil(NNODES / 128)
#define CAP 4096 // edges per bucket frame (mean 2046, sd 45 -> >40 sigma headroom)
#define NZ NB    // ints to zero (bcur)
#define LP 136   // LDS row pitch in shorts (272B: 16B-aligned, 2-way max bank alias)
#define NAB 25000 // agg2/pool blocks (N/4)

typedef short short8v __attribute__((ext_vector_type(8)));
typedef float float4v __attribute__((ext_vector_type(4)));

__device__ inline short f2h_s(float f) {
    __half h = __float2half(f);
    return __builtin_bit_cast(short, h);
}
__device__ inline ushort f2h_u(float f) {
    __half h = __float2half(f);
    return __builtin_bit_cast(ushort, h);
}
__device__ inline __half2 u2h2(uint u) { return __builtin_bit_cast(__half2, u); }
__device__ inline uint h22u(__half2 h) { return __builtin_bit_cast(uint, h); }

// ---------------- setup: zero ∪ prepw ∪ bounds (block-range partitioned) ----------------

__global__ __launch_bounds__(256) void k_setup(int* __restrict__ zb,
                                               const float* __restrict__ W1,
                                               const float* __restrict__ W2,
                                               short8v* __restrict__ o1,
                                               short8v* __restrict__ o2,
                                               const int* __restrict__ batch,
                                               int* __restrict__ gstart,
                                               int* __restrict__ gend) {
    int b = blockIdx.x, t = threadIdx.x;
    if (b < 4) {
        int i = b * 256 + t;
        if (i < NZ) zb[i] = 0;
    } else if (b < 6) {
        const float* W = (b == 5) ? W2 : W1;
        short8v* o = (b == 5) ? o2 : o1;
        for (int s = t; s < 2048; s += 256) {
            int p = s >> 6, l = s & 63;
            int kb = (p >> 3) * 32 + ((l >> 4) * 8);
            int j = (p & 7) * 16 + (l & 15);
            short8v v;
            #pragma unroll
            for (int i = 0; i < 8; ++i)
                v[i] = f2h_s(W[(size_t)(kb + i) * 128 + j]);
            o[s] = v;
        }
    } else {
        int i = (b - 6) * 256 + t;
        if (i < NNODES) {
            int bb = batch[i];
            if (i == 0 || batch[i - 1] != bb) gstart[bb] = i;
            if (i == NNODES - 1 || batch[i + 1] != bb) gend[bb] = i + 1;
        }
    }
}

// ---------------- P1: bucket scatter with direct atomic reservation ----------------

#define P1_EPT 8
__global__ __launch_bounds__(256) void k_bscatter(const int* __restrict__ src,
                                                  const int* __restrict__ dst,
                                                  int* __restrict__ bcur,
                                                  uint* __restrict__ pairs, int E) {
    __shared__ int h[NB];
    __shared__ int base[NB];
    int t = threadIdx.x;
    long long c0 = (long long)blockIdx.x * 2048;
    if (c0 >= E) return;
    for (int i = t; i < NB; i += 256) h[i] = 0;
    __syncthreads();
    int myb[P1_EPT], mylp[P1_EPT];
    uint myv[P1_EPT];
    #pragma unroll
    for (int k = 0; k < P1_EPT; ++k) {
        long long e = c0 + t + k * 256;
        if (e < E) {
            int d = dst[e];
            myv[k] = (uint)src[e] | ((uint)(d & (BRANGE - 1)) << 24);
            myb[k] = d >> BSHIFT;
            mylp[k] = atomicAdd(&h[myb[k]], 1);
        } else myb[k] = -1;
    }
    __syncthreads();
    for (int i = t; i < NB; i += 256)
        base[i] = h[i] ? atomicAdd(&bcur[i], h[i]) : 0;
    __syncthreads();
    #pragma unroll
    for (int k = 0; k < P1_EPT; ++k)
        if (myb[k] >= 0) {
            int pos = base[myb[k]] + mylp[k];
            if (pos < CAP)
                pairs[(size_t)myb[k] * CAP + pos] = myv[k];
        }
}

// ---------------- fused per-bucket: histogram -> dinv + node ranges -> CSR scatter ----------------

__global__ __launch_bounds__(256) void k_build(const uint* __restrict__ pairs,
                                               const int* __restrict__ bcur,
                                               int2* __restrict__ nr,
                                               float* __restrict__ dinv,
                                               int* __restrict__ csr, int N) {
    __shared__ int h[256];
    __shared__ int sh[256];
    __shared__ int cur[BRANGE];
    int b = blockIdx.x, t = threadIdx.x;
    h[t] = 0;
    __syncthreads();
    const int p0 = b * CAP;
    const int cntb = min(bcur[b], CAP);
    for (int p = t; p < cntb; p += 256)
        atomicAdd(&h[pairs[p0 + p] >> 24], 1);
    __syncthreads();
    int myh = h[t];
    sh[t] = myh;
    __syncthreads();
    #pragma unroll
    for (int d = 1; d < 256; d <<= 1) {
        int val = (t >= d) ? sh[t - d] : 0;
        __syncthreads();
        sh[t] += val;
        __syncthreads();
    }
    int excl = sh[t] - myh;
    int node = (b << BSHIFT) + t;
    if (t < BRANGE) {
        cur[t] = p0 + excl;
        if (node < N) {
            nr[node] = make_int2(p0 + excl, p0 + excl + myh);
            dinv[node] = rsqrtf((float)(myh + 1));
        }
    }
    __syncthreads();
    for (int p = t; p < cntb; p += 256) {
        uint pr = pairs[p0 + p];
        int pos = atomicAdd(&cur[pr >> 24], 1);
        csr[pos] = (int)(pr & 0x00FFFFFFu);
    }
}

// ---------------- GEMM1 (f32 in): msg1[n,128] = (X @ W1) * dinv[row], fp16 out ----------------

__global__ __launch_bounds__(256) void k_gemm_f32(const float* __restrict__ X,
                                                  const short8v* __restrict__ wf,
                                                  const float* __restrict__ dinv,
                                                  ushort* __restrict__ Y, int nrows) {
    __shared__ short8v sW[2048];
    const int tid = threadIdx.x;
    const int lane = tid & 63;
    const int w = tid >> 6;

    for (int s = tid; s < 2048; s += 256) sW[s] = wf[s];
    __syncthreads();

    const int row0 = blockIdx.x * 64 + w * 16;
    const int arow = row0 + (lane & 15);
    float4v acc[8];
    #pragma unroll
    for (int ct = 0; ct < 8; ++ct) acc[ct] = (float4v)0.f;

    #pragma unroll
    for (int kk = 0; kk < 4; ++kk) {
        short8v a = (short8v)0;
        if (arow < nrows) {
            const float* xp = X + (size_t)arow * 128 + kk * 32 + ((lane >> 4) * 8);
            float4 f0 = ((const float4*)xp)[0];
            float4 f1 = ((const float4*)xp)[1];
            a[0] = f2h_s(f0.x); a[1] = f2h_s(f0.y);
            a[2] = f2h_s(f0.z); a[3] = f2h_s(f0.w);
            a[4] = f2h_s(f1.x); a[5] = f2h_s(f1.y);
            a[6] = f2h_s(f1.z); a[7] = f2h_s(f1.w);
        }
        #pragma unroll
        for (int ct = 0; ct < 8; ++ct)
            acc[ct] = __builtin_amdgcn_mfma_f32_16x16x32_f16(a, sW[(kk * 8 + ct) * 64 + lane],
                                                             acc[ct], 0, 0, 0);
    }

    const int orow = row0 + ((lane >> 4) << 2);
    #pragma unroll
    for (int r = 0; r < 4; ++r) {
        int row = orow + r;
        if (row < nrows) {
            float dr = dinv[row];
            #pragma unroll
            for (int ct = 0; ct < 8; ++ct)
                Y[(size_t)row * 128 + ct * 16 + (lane & 15)] = f2h_u(acc[ct][r] * dr);
        }
    }
}

// ---------------- FUSED agg1 + GEMM2 ----------------

__global__ __launch_bounds__(256, 6) void k_agg_gemm(const uint* __restrict__ msg,
                                                     const float* __restrict__ dinv,
                                                     const int2* __restrict__ nr,
                                                     const int* __restrict__ csr,
                                                     const float* __restrict__ bias,
                                                     const short8v* __restrict__ wf,
                                                     ushort* __restrict__ Y, int n) {
    __shared__ ushort ht[64 * LP];  // 17.4 KB
    const int t = threadIdx.x;
    const int lane = t & 63;
    const int w = t >> 6;
    const int row0 = blockIdx.x * 64;
    const float bx = bias[lane * 2];
    const float by = bias[lane * 2 + 1];

    // phase 1: aggregate 16 nodes per wave
    for (int i = 0; i < 16; ++i) {
        const int r = w * 16 + i;
        const int wid = row0 + r;
        uint o = 0u;
        if (wid < n) {
            __half2 a0 = u2h2(msg[(size_t)wid * 64 + lane]);
            __half2 a1 = u2h2(0u), a2 = u2h2(0u);
            const int2 rg = nr[wid];
            const int e0 = rg.x, e1 = rg.y;
            for (int e = e0; e < e1; e += 64) {
                int me = e + lane;
                int sidx = (me < e1) ? csr[me] : 0;
                int cnt = min(64, e1 - e);
                for (int kb = 0; kb < cnt; kb += 6) {
                    int lim = cnt - 1;
                    int s0 = __shfl(sidx, min(kb + 0, lim));
                    int s1 = __shfl(sidx, min(kb + 1, lim));
                    int s2 = __shfl(sidx, min(kb + 2, lim));
                    int s3 = __shfl(sidx, min(kb + 3, lim));
                    int s4 = __shfl(sidx, min(kb + 4, lim));
                    int s5 = __shfl(sidx, min(kb + 5, lim));
                    uint u0 = msg[(size_t)s0 * 64 + lane];
                    uint u1 = msg[(size_t)s1 * 64 + lane];
                    uint u2 = msg[(size_t)s2 * 64 + lane];
                    uint u3 = msg[(size_t)s3 * 64 + lane];
                    uint u4 = msg[(size_t)s4 * 64 + lane];
                    uint u5 = msg[(size_t)s5 * 64 + lane];
                    u1 = (kb + 1 < cnt) ? u1 : 0u;
                    u2 = (kb + 2 < cnt) ? u2 : 0u;
                    u3 = (kb + 3 < cnt) ? u3 : 0u;
                    u4 = (kb + 4 < cnt) ? u4 : 0u;
                    u5 = (kb + 5 < cnt) ? u5 : 0u;
                    a0 = __hadd2(a0, u2h2(u0));
                    a1 = __hadd2(a1, u2h2(u1));
                    a2 = __hadd2(a2, u2h2(u2));
                    a0 = __hadd2(a0, u2h2(u3));
                    a1 = __hadd2(a1, u2h2(u4));
                    a2 = __hadd2(a2, u2h2(u5));
                }
            }
            __half2 acc = __hadd2(__hadd2(a0, a1), a2);
            float2 f = __half22float2(acc);
            float dd = dinv[wid];
            float ax = fmaxf(f.x * dd + bx, 0.f);
            float ay = fmaxf(f.y * dd + by, 0.f);
            o = h22u(__floats2half2_rn(ax, ay));
        }
        *(uint*)&ht[r * LP + lane * 2] = o;
    }
    __syncthreads();

    // phase 2: GEMM on the 64x128 LDS tile; W2 fragments from global (L2-hot)
    float4v acc[8];
    #pragma unroll
    for (int ct = 0; ct < 8; ++ct) acc[ct] = (float4v)0.f;
    const int arow = w * 16 + (lane & 15);
    #pragma unroll 1
    for (int kk = 0; kk < 4; ++kk) {
        short8v a = *(const short8v*)&ht[arow * LP + kk * 32 + ((lane >> 4) * 8)];
        #pragma unroll
        for (int ct = 0; ct < 8; ++ct)
            acc[ct] = __builtin_amdgcn_mfma_f32_16x16x32_f16(a, wf[(kk * 8 + ct) * 64 + lane],
                                                             acc[ct], 0, 0, 0);
    }
    const int orow = row0 + w * 16 + ((lane >> 4) << 2);
    #pragma unroll
    for (int r = 0; r < 4; ++r) {
        int row = orow + r;
        if (row < n) {
            float dr = dinv[row];
            #pragma unroll
            for (int ct = 0; ct < 8; ++ct)
                Y[(size_t)row * 128 + ct * 16 + (lane & 15)] = f2h_u(acc[ct][r] * dr);
        }
    }
}

// ---------------- FUSED agg2 + pool: per-block (4 nodes) partial sums, A/B by graph ----------------

__global__ __launch_bounds__(256) void k_agg_pool(const uint* __restrict__ msg,
                                                  const float* __restrict__ dinv,
                                                  const int2* __restrict__ nr,
                                                  const int* __restrict__ csr,
                                                  const int* __restrict__ batch,
                                                  float* __restrict__ pA,
                                                  float* __restrict__ pB) {
    __shared__ float red[4][128];
    __shared__ int selw[4];
    const int blk = blockIdx.x;
    const int t = threadIdx.x;
    const int lane = t & 63;
    const int w = t >> 6;
    const int wid = blk * 4 + w;  // N % 4 == 0, always valid

    __half2 a0 = u2h2(msg[(size_t)wid * 64 + lane]);
    __half2 a1 = u2h2(0u), a2 = u2h2(0u);
    const int2 rg = nr[wid];
    const int e0 = rg.x, e1 = rg.y;
    for (int e = e0; e < e1; e += 64) {
        int me = e + lane;
        int sidx = (me < e1) ? csr[me] : 0;
        int cnt = min(64, e1 - e);
        for (int kb = 0; kb < cnt; kb += 6) {
            int lim = cnt - 1;
            int s0 = __shfl(sidx, min(kb + 0, lim));
            int s1 = __shfl(sidx, min(kb + 1, lim));
            int s2 = __shfl(sidx, min(kb + 2, lim));
            int s3 = __shfl(sidx, min(kb + 3, lim));
            int s4 = __shfl(sidx, min(kb + 4, lim));
            int s5 = __shfl(sidx, min(kb + 5, lim));
            uint u0 = msg[(size_t)s0 * 64 + lane];
            uint u1 = msg[(size_t)s1 * 64 + lane];
            uint u2 = msg[(size_t)s2 * 64 + lane];
            uint u3 = msg[(size_t)s3 * 64 + lane];
            uint u4 = msg[(size_t)s4 * 64 + lane];
            uint u5 = msg[(size_t)s5 * 64 + lane];
            u1 = (kb + 1 < cnt) ? u1 : 0u;
            u2 = (kb + 2 < cnt) ? u2 : 0u;
            u3 = (kb + 3 < cnt) ? u3 : 0u;
            u4 = (kb + 4 < cnt) ? u4 : 0u;
            u5 = (kb + 5 < cnt) ? u5 : 0u;
            a0 = __hadd2(a0, u2h2(u0));
            a1 = __hadd2(a1, u2h2(u1));
            a2 = __hadd2(a2, u2h2(u2));
            a0 = __hadd2(a0, u2h2(u3));
            a1 = __hadd2(a1, u2h2(u4));
            a2 = __hadd2(a2, u2h2(u5));
        }
    }
    __half2 acc = __hadd2(__hadd2(a0, a1), a2);
    float2 f = __half22float2(acc);
    float dd = dinv[wid];
    red[w][lane * 2] = f.x * dd;
    red[w][lane * 2 + 1] = f.y * dd;
    if (lane == 0) selw[w] = (batch[wid] != batch[blk * 4]) ? 1 : 0;
    __syncthreads();
    if (t < 128) {
        float a = 0.f, b = 0.f;
        #pragma unroll
        for (int ww = 0; ww < 4; ++ww) {
            float v = red[ww][t];
            if (selw[ww]) b += v; else a += v;
        }
        pA[(size_t)blk * 128 + t] = a;
        if (selw[0] | selw[1] | selw[2] | selw[3])
            pB[(size_t)blk * 128 + t] = b;
    }
}

// ---------------- final: per-graph reduce (512 threads, 4-way strided) + linear head ----------------
// Only a graph's FIRST block b0 can start in the previous graph; all blocks b0+1..b1 are pure pA.

__global__ __launch_bounds__(512) void k_final(const float* __restrict__ pA,
                                               const float* __restrict__ pB,
                                               const int* __restrict__ batch,
                                               const int* __restrict__ gstart,
                                               const int* __restrict__ gend,
                                               const float* __restrict__ b2,
                                               const float* __restrict__ linW,
                                               const float* __restrict__ linb,
                                               float* __restrict__ out) {
    __shared__ float sq[4][128];
    __shared__ float red[128][8];
    int g = blockIdx.x;
    int t = threadIdx.x;
    int c = t & 127;   // channel
    int q = t >> 7;    // quarter 0..3
    int b0 = gstart[g] >> 2;
    int b1 = (gend[g] - 1) >> 2;
    float v = 0.f;
    #pragma unroll 4
    for (int b = b0 + 1 + q; b <= b1; b += 4)
        v += pA[(size_t)b * 128 + c];
    if (q == 0)
        v += ((batch[b0 * 4] != g) ? pB : pA)[(size_t)b0 * 128 + c];
    sq[q][c] = v;
    __syncthreads();
    if (t < 128) {
        float sv = sq[0][t] + sq[1][t] + sq[2][t] + sq[3][t];
        float cnt = (float)(gend[g] - gstart[g]);
        sv = sv / fmaxf(cnt, 1.0f) + b2[t];
        #pragma unroll
        for (int k = 0; k < 8; ++k) red[t][k] = sv * linW[(size_t)t * 8 + k];
    }
    __syncthreads();
    #pragma unroll
    for (int st = 64; st > 0; st >>= 1) {
        if (t < st) {
            #pragma unroll
            for (int k = 0; k < 8; ++k) red[t][k] += red[t + st][k];
        }
        __syncthreads();
    }
    if (t < 8) out[(size_t)g * 8 + t] = red[0][t] + linb[t];
}

// ---------------- launch ----------------

extern "C" void kernel_launch(void* const* d_in, const int* in_sizes, int n_in,
                              void* d_out, int out_size, void* d_ws, size_t ws_size,
                              hipStream_t stream) {
    const float* x     = (const float*)d_in[0];
    const int*   ei    = (const int*)d_in[1];  // [2,E]: src = ei, dst = ei+E
    const int*   batch = (const int*)d_in[2];
    const float* W1    = (const float*)d_in[3];
    const float* b1    = (const float*)d_in[4];
    const float* W2    = (const float*)d_in[5];
    const float* b2    = (const float*)d_in[6];
    const float* linW  = (const float*)d_in[7];
    const float* linb  = (const float*)d_in[8];
    float* out = (float*)d_out;

    const int N = NNODES, E = NEDGES;
    const int* src = ei;
    const int* dst = ei + E;

    char* ws = (char*)d_ws;
    uint*  bufA16 = (uint*)ws;     ws += (size_t)N * 64 * 4;   // msg1 (fp16), 25.6MB
    uint*  bufH16 = (uint*)ws;     ws += (size_t)N * 64 * 4;   // msg2 (fp16), 25.6MB
    float* dinv   = (float*)ws;    ws += (size_t)N * 4;
    int2*  nr     = (int2*)ws;     ws += (size_t)N * 8;        // per-node (start,end)
    int*   csr    = (int*)ws;      ws += (size_t)NB * CAP * 4; // 12.8MB bucket frames
    int*   bcur   = (int*)ws;      ws += NB * 4;               // zero region
    int*   gstart = (int*)ws;      ws += NGRAPHS * 4;
    int*   gend   = (int*)ws;      ws += NGRAPHS * 4;
    short8v* wf1  = (short8v*)ws;  ws += 2048 * 16;            // fragment-ordered W1 (32KB)
    short8v* wf2  = (short8v*)ws;  ws += 2048 * 16;            // fragment-ordered W2 (32KB)
    float* pA     = (float*)ws;    ws += (size_t)NAB * 128 * 4;  // 12.8MB
    float* pB     = (float*)ws;    ws += (size_t)NAB * 128 * 4;  // 12.8MB
    // pairs aliases bufH16 (12.8MB < 25.6MB): CSR build completes before msg2 written
    uint*  pairs  = (uint*)bufH16;

    const int B = 256;

    // setup: zero(4) + prepw(2) + bounds(391) = 397 blocks
    k_setup<<<397, B, 0, stream>>>(bcur, W1, W2, wf1, wf2, batch, gstart, gend);

    // CSR build
    k_bscatter<<<(E + 2047) / 2048, B, 0, stream>>>(src, dst, bcur, pairs, E);
    k_build<<<NB, B, 0, stream>>>(pairs, bcur, nr, dinv, csr, N);

    const int gemmGrid = (N + 63) / 64;

    // layer 1 GEMM: msg1 = (x @ W1) * dinv
    k_gemm_f32<<<gemmGrid, B, 0, stream>>>(x, wf1, dinv, (ushort*)bufA16, N);

    // fused agg1 + GEMM2: msg2 = (relu(agg(msg1)+b1) @ W2) * dinv
    k_agg_gemm<<<gemmGrid, B, 0, stream>>>(bufA16, dinv, nr, csr, b1, wf2,
                                           (ushort*)bufH16, N);

    // fused agg2 + pool: per-block partial sums of h2
    k_agg_pool<<<NAB, B, 0, stream>>>(bufH16, dinv, nr, csr, batch, pA, pB);

    // per-graph reduce + head
    k_final<<<NGRAPHS, 512, 0, stream>>>(pA, pB, batch, gstart, gend, b2, linW, linb, out);
}

// Round 17
// 206.278 us; speedup vs baseline: 1.6339x; 1.0453x over previous
//
#include <hip/hip_runtime.h>
#include <hip/hip_fp16.h>
#include <cstdint>
#include <cstddef>

#define NNODES 100000
#define NEDGES 1600000
#define NGRAPHS 64
#define BSHIFT 7
#define BRANGE 128
#define NB 782   // ceil(NNODES / 128)
#define CAP 4096 // edges per bucket frame (mean 2046, sd 45 -> >40 sigma headroom)
#define NZ NB    // ints to zero (bcur)
#define LP 136   // LDS row pitch in shorts (272B: 16B-aligned, 2-way max bank alias)
#define NAB 25000 // agg2/pool blocks (N/4)

typedef short short8v __attribute__((ext_vector_type(8)));
typedef float float4v __attribute__((ext_vector_type(4)));

__device__ inline short f2h_s(float f) {
    __half h = __float2half(f);
    return __builtin_bit_cast(short, h);
}
__device__ inline ushort f2h_u(float f) {
    __half h = __float2half(f);
    return __builtin_bit_cast(ushort, h);
}
__device__ inline __half2 u2h2(uint u) { return __builtin_bit_cast(__half2, u); }
__device__ inline uint h22u(__half2 h) { return __builtin_bit_cast(uint, h); }

// ---------------- setup: zero ∪ prepw ∪ bounds (block-range partitioned) ----------------

__global__ __launch_bounds__(256) void k_setup(int* __restrict__ zb,
                                               const float* __restrict__ W1,
                                               const float* __restrict__ W2,
                                               short8v* __restrict__ o1,
                                               short8v* __restrict__ o2,
                                               const int* __restrict__ batch,
                                               int* __restrict__ gstart,
                                               int* __restrict__ gend) {
    int b = blockIdx.x, t = threadIdx.x;
    if (b < 4) {
        int i = b * 256 + t;
        if (i < NZ) zb[i] = 0;
    } else if (b < 6) {
        const float* W = (b == 5) ? W2 : W1;
        short8v* o = (b == 5) ? o2 : o1;
        for (int s = t; s < 2048; s += 256) {
            int p = s >> 6, l = s & 63;
            int kb = (p >> 3) * 32 + ((l >> 4) * 8);
            int j = (p & 7) * 16 + (l & 15);
            short8v v;
            #pragma unroll
            for (int i = 0; i < 8; ++i)
                v[i] = f2h_s(W[(size_t)(kb + i) * 128 + j]);
            o[s] = v;
        }
    } else {
        int i = (b - 6) * 256 + t;
        if (i < NNODES) {
            int bb = batch[i];
            if (i == 0 || batch[i - 1] != bb) gstart[bb] = i;
            if (i == NNODES - 1 || batch[i + 1] != bb) gend[bb] = i + 1;
        }
    }
}

// ---------------- P1: bucket scatter, 4096 edges/block, direct atomic reservation ----------------

#define P1_EPT 16
__global__ __launch_bounds__(256) void k_bscatter(const int* __restrict__ src,
                                                  const int* __restrict__ dst,
                                                  int* __restrict__ bcur,
                                                  uint* __restrict__ pairs, int E) {
    __shared__ int h[NB];
    __shared__ int base[NB];
    int t = threadIdx.x;
    long long c0 = (long long)blockIdx.x * 4096;
    if (c0 >= E) return;
    for (int i = t; i < NB; i += 256) h[i] = 0;
    __syncthreads();
    int myb[P1_EPT], mylp[P1_EPT];
    uint myv[P1_EPT];
    #pragma unroll
    for (int k = 0; k < P1_EPT; ++k) {
        long long e = c0 + t + k * 256;
        if (e < E) {
            int d = dst[e];
            myv[k] = (uint)src[e] | ((uint)(d & (BRANGE - 1)) << 24);
            myb[k] = d >> BSHIFT;
            mylp[k] = atomicAdd(&h[myb[k]], 1);
        } else myb[k] = -1;
    }
    __syncthreads();
    for (int i = t; i < NB; i += 256)
        base[i] = h[i] ? atomicAdd(&bcur[i], h[i]) : 0;
    __syncthreads();
    #pragma unroll
    for (int k = 0; k < P1_EPT; ++k)
        if (myb[k] >= 0) {
            int pos = base[myb[k]] + mylp[k];
            if (pos < CAP)
                pairs[(size_t)myb[k] * CAP + pos] = myv[k];
        }
}

// ---------------- fused per-bucket: histogram -> dinv + node ranges -> CSR scatter ----------------

__global__ __launch_bounds__(256) void k_build(const uint* __restrict__ pairs,
                                               const int* __restrict__ bcur,
                                               int2* __restrict__ nr,
                                               float* __restrict__ dinv,
                                               int* __restrict__ csr, int N) {
    __shared__ int h[256];
    __shared__ int sh[256];
    __shared__ int cur[BRANGE];
    int b = blockIdx.x, t = threadIdx.x;
    h[t] = 0;
    __syncthreads();
    const int p0 = b * CAP;
    const int cntb = min(bcur[b], CAP);
    for (int p = t; p < cntb; p += 256)
        atomicAdd(&h[pairs[p0 + p] >> 24], 1);
    __syncthreads();
    int myh = h[t];
    sh[t] = myh;
    __syncthreads();
    #pragma unroll
    for (int d = 1; d < 256; d <<= 1) {
        int val = (t >= d) ? sh[t - d] : 0;
        __syncthreads();
        sh[t] += val;
        __syncthreads();
    }
    int excl = sh[t] - myh;
    int node = (b << BSHIFT) + t;
    if (t < BRANGE) {
        cur[t] = p0 + excl;
        if (node < N) {
            nr[node] = make_int2(p0 + excl, p0 + excl + myh);
            dinv[node] = rsqrtf((float)(myh + 1));
        }
    }
    __syncthreads();
    for (int p = t; p < cntb; p += 256) {
        uint pr = pairs[p0 + p];
        int pos = atomicAdd(&cur[pr >> 24], 1);
        csr[pos] = (int)(pr & 0x00FFFFFFu);
    }
}

// ---------------- GEMM1 (f32 in): msg1[n,128] = (X @ W1) * dinv[row], fp16 out ----------------

__global__ __launch_bounds__(256) void k_gemm_f32(const float* __restrict__ X,
                                                  const short8v* __restrict__ wf,
                                                  const float* __restrict__ dinv,
                                                  ushort* __restrict__ Y, int nrows) {
    __shared__ short8v sW[2048];
    const int tid = threadIdx.x;
    const int lane = tid & 63;
    const int w = tid >> 6;

    for (int s = tid; s < 2048; s += 256) sW[s] = wf[s];
    __syncthreads();

    const int row0 = blockIdx.x * 64 + w * 16;
    const int arow = row0 + (lane & 15);
    float4v acc[8];
    #pragma unroll
    for (int ct = 0; ct < 8; ++ct) acc[ct] = (float4v)0.f;

    #pragma unroll
    for (int kk = 0; kk < 4; ++kk) {
        short8v a = (short8v)0;
        if (arow < nrows) {
            const float* xp = X + (size_t)arow * 128 + kk * 32 + ((lane >> 4) * 8);
            float4 f0 = ((const float4*)xp)[0];
            float4 f1 = ((const float4*)xp)[1];
            a[0] = f2h_s(f0.x); a[1] = f2h_s(f0.y);
            a[2] = f2h_s(f0.z); a[3] = f2h_s(f0.w);
            a[4] = f2h_s(f1.x); a[5] = f2h_s(f1.y);
            a[6] = f2h_s(f1.z); a[7] = f2h_s(f1.w);
        }
        #pragma unroll
        for (int ct = 0; ct < 8; ++ct)
            acc[ct] = __builtin_amdgcn_mfma_f32_16x16x32_f16(a, sW[(kk * 8 + ct) * 64 + lane],
                                                             acc[ct], 0, 0, 0);
    }

    const int orow = row0 + ((lane >> 4) << 2);
    #pragma unroll
    for (int r = 0; r < 4; ++r) {
        int row = orow + r;
        if (row < nrows) {
            float dr = dinv[row];
            #pragma unroll
            for (int ct = 0; ct < 8; ++ct)
                Y[(size_t)row * 128 + ct * 16 + (lane & 15)] = f2h_u(acc[ct][r] * dr);
        }
    }
}

// ---------------- FUSED agg1 + GEMM2 ----------------

__global__ __launch_bounds__(256, 8) void k_agg_gemm(const uint* __restrict__ msg,
                                                     const float* __restrict__ dinv,
                                                     const int2* __restrict__ nr,
                                                     const int* __restrict__ csr,
                                                     const float* __restrict__ bias,
                                                     const short8v* __restrict__ wf,
                                                     ushort* __restrict__ Y, int n) {
    __shared__ ushort ht[64 * LP];  // 17.4 KB
    const int t = threadIdx.x;
    const int lane = t & 63;
    const int w = t >> 6;
    const int row0 = blockIdx.x * 64;
    const float bx = bias[lane * 2];
    const float by = bias[lane * 2 + 1];

    // phase 1: aggregate 16 nodes per wave
    for (int i = 0; i < 16; ++i) {
        const int r = w * 16 + i;
        const int wid = row0 + r;
        uint o = 0u;
        if (wid < n) {
            __half2 a0 = u2h2(msg[(size_t)wid * 64 + lane]);
            __half2 a1 = u2h2(0u), a2 = u2h2(0u);
            const int2 rg = nr[wid];
            const int e0 = rg.x, e1 = rg.y;
            for (int e = e0; e < e1; e += 64) {
                int me = e + lane;
                int sidx = (me < e1) ? csr[me] : 0;
                int cnt = min(64, e1 - e);
                for (int kb = 0; kb < cnt; kb += 6) {
                    int lim = cnt - 1;
                    int s0 = __shfl(sidx, min(kb + 0, lim));
                    int s1 = __shfl(sidx, min(kb + 1, lim));
                    int s2 = __shfl(sidx, min(kb + 2, lim));
                    int s3 = __shfl(sidx, min(kb + 3, lim));
                    int s4 = __shfl(sidx, min(kb + 4, lim));
                    int s5 = __shfl(sidx, min(kb + 5, lim));
                    uint u0 = msg[(size_t)s0 * 64 + lane];
                    uint u1 = msg[(size_t)s1 * 64 + lane];
                    uint u2 = msg[(size_t)s2 * 64 + lane];
                    uint u3 = msg[(size_t)s3 * 64 + lane];
                    uint u4 = msg[(size_t)s4 * 64 + lane];
                    uint u5 = msg[(size_t)s5 * 64 + lane];
                    u1 = (kb + 1 < cnt) ? u1 : 0u;
                    u2 = (kb + 2 < cnt) ? u2 : 0u;
                    u3 = (kb + 3 < cnt) ? u3 : 0u;
                    u4 = (kb + 4 < cnt) ? u4 : 0u;
                    u5 = (kb + 5 < cnt) ? u5 : 0u;
                    a0 = __hadd2(a0, u2h2(u0));
                    a1 = __hadd2(a1, u2h2(u1));
                    a2 = __hadd2(a2, u2h2(u2));
                    a0 = __hadd2(a0, u2h2(u3));
                    a1 = __hadd2(a1, u2h2(u4));
                    a2 = __hadd2(a2, u2h2(u5));
                }
            }
            __half2 acc = __hadd2(__hadd2(a0, a1), a2);
            float2 f = __half22float2(acc);
            float dd = dinv[wid];
            float ax = fmaxf(f.x * dd + bx, 0.f);
            float ay = fmaxf(f.y * dd + by, 0.f);
            o = h22u(__floats2half2_rn(ax, ay));
        }
        *(uint*)&ht[r * LP + lane * 2] = o;
    }
    __syncthreads();

    // phase 2: GEMM on the 64x128 LDS tile; W2 fragments from global (L2-hot)
    float4v acc[8];
    #pragma unroll
    for (int ct = 0; ct < 8; ++ct) acc[ct] = (float4v)0.f;
    const int arow = w * 16 + (lane & 15);
    #pragma unroll 1
    for (int kk = 0; kk < 4; ++kk) {
        short8v a = *(const short8v*)&ht[arow * LP + kk * 32 + ((lane >> 4) * 8)];
        #pragma unroll
        for (int ct = 0; ct < 8; ++ct)
            acc[ct] = __builtin_amdgcn_mfma_f32_16x16x32_f16(a, wf[(kk * 8 + ct) * 64 + lane],
                                                             acc[ct], 0, 0, 0);
    }
    const int orow = row0 + w * 16 + ((lane >> 4) << 2);
    #pragma unroll
    for (int r = 0; r < 4; ++r) {
        int row = orow + r;
        if (row < n) {
            float dr = dinv[row];
            #pragma unroll
            for (int ct = 0; ct < 8; ++ct)
                Y[(size_t)row * 128 + ct * 16 + (lane & 15)] = f2h_u(acc[ct][r] * dr);
        }
    }
}

// ---------------- FUSED agg2 + pool: per-block (4 nodes) partial sums, A/B by graph ----------------

__global__ __launch_bounds__(256) void k_agg_pool(const uint* __restrict__ msg,
                                                  const float* __restrict__ dinv,
                                                  const int2* __restrict__ nr,
                                                  const int* __restrict__ csr,
                                                  const int* __restrict__ batch,
                                                  float* __restrict__ pA,
                                                  float* __restrict__ pB) {
    __shared__ float red[4][128];
    __shared__ int selw[4];
    const int blk = blockIdx.x;
    const int t = threadIdx.x;
    const int lane = t & 63;
    const int w = t >> 6;
    const int wid = blk * 4 + w;  // N % 4 == 0, always valid

    __half2 a0 = u2h2(msg[(size_t)wid * 64 + lane]);
    __half2 a1 = u2h2(0u), a2 = u2h2(0u);
    const int2 rg = nr[wid];
    const int e0 = rg.x, e1 = rg.y;
    for (int e = e0; e < e1; e += 64) {
        int me = e + lane;
        int sidx = (me < e1) ? csr[me] : 0;
        int cnt = min(64, e1 - e);
        for (int kb = 0; kb < cnt; kb += 6) {
            int lim = cnt - 1;
            int s0 = __shfl(sidx, min(kb + 0, lim));
            int s1 = __shfl(sidx, min(kb + 1, lim));
            int s2 = __shfl(sidx, min(kb + 2, lim));
            int s3 = __shfl(sidx, min(kb + 3, lim));
            int s4 = __shfl(sidx, min(kb + 4, lim));
            int s5 = __shfl(sidx, min(kb + 5, lim));
            uint u0 = msg[(size_t)s0 * 64 + lane];
            uint u1 = msg[(size_t)s1 * 64 + lane];
            uint u2 = msg[(size_t)s2 * 64 + lane];
            uint u3 = msg[(size_t)s3 * 64 + lane];
            uint u4 = msg[(size_t)s4 * 64 + lane];
            uint u5 = msg[(size_t)s5 * 64 + lane];
            u1 = (kb + 1 < cnt) ? u1 : 0u;
            u2 = (kb + 2 < cnt) ? u2 : 0u;
            u3 = (kb + 3 < cnt) ? u3 : 0u;
            u4 = (kb + 4 < cnt) ? u4 : 0u;
            u5 = (kb + 5 < cnt) ? u5 : 0u;
            a0 = __hadd2(a0, u2h2(u0));
            a1 = __hadd2(a1, u2h2(u1));
            a2 = __hadd2(a2, u2h2(u2));
            a0 = __hadd2(a0, u2h2(u3));
            a1 = __hadd2(a1, u2h2(u4));
            a2 = __hadd2(a2, u2h2(u5));
        }
    }
    __half2 acc = __hadd2(__hadd2(a0, a1), a2);
    float2 f = __half22float2(acc);
    float dd = dinv[wid];
    red[w][lane * 2] = f.x * dd;
    red[w][lane * 2 + 1] = f.y * dd;
    if (lane == 0) selw[w] = (batch[wid] != batch[blk * 4]) ? 1 : 0;
    __syncthreads();
    if (t < 128) {
        float a = 0.f, b = 0.f;
        #pragma unroll
        for (int ww = 0; ww < 4; ++ww) {
            float v = red[ww][t];
            if (selw[ww]) b += v; else a += v;
        }
        pA[(size_t)blk * 128 + t] = a;
        if (selw[0] | selw[1] | selw[2] | selw[3])
            pB[(size_t)blk * 128 + t] = b;
    }
}

// ---------------- final: per-graph reduce (512 threads, 4-way strided) + linear head ----------------

__global__ __launch_bounds__(512) void k_final(const float* __restrict__ pA,
                                               const float* __restrict__ pB,
                                               const int* __restrict__ batch,
                                               const int* __restrict__ gstart,
                                               const int* __restrict__ gend,
                                               const float* __restrict__ b2,
                                               const float* __restrict__ linW,
                                               const float* __restrict__ linb,
                                               float* __restrict__ out) {
    __shared__ float sq[4][128];
    __shared__ float red[128][8];
    int g = blockIdx.x;
    int t = threadIdx.x;
    int c = t & 127;   // channel
    int q = t >> 7;    // quarter 0..3
    int b0 = gstart[g] >> 2;
    int b1 = (gend[g] - 1) >> 2;
    float v = 0.f;
    #pragma unroll 4
    for (int b = b0 + 1 + q; b <= b1; b += 4)
        v += pA[(size_t)b * 128 + c];
    if (q == 0)
        v += ((batch[b0 * 4] != g) ? pB : pA)[(size_t)b0 * 128 + c];
    sq[q][c] = v;
    __syncthreads();
    if (t < 128) {
        float sv = sq[0][t] + sq[1][t] + sq[2][t] + sq[3][t];
        float cnt = (float)(gend[g] - gstart[g]);
        sv = sv / fmaxf(cnt, 1.0f) + b2[t];
        #pragma unroll
        for (int k = 0; k < 8; ++k) red[t][k] = sv * linW[(size_t)t * 8 + k];
    }
    __syncthreads();
    #pragma unroll
    for (int st = 64; st > 0; st >>= 1) {
        if (t < st) {
            #pragma unroll
            for (int k = 0; k < 8; ++k) red[t][k] += red[t + st][k];
        }
        __syncthreads();
    }
    if (t < 8) out[(size_t)g * 8 + t] = red[0][t] + linb[t];
}

// ---------------- launch ----------------

extern "C" void kernel_launch(void* const* d_in, const int* in_sizes, int n_in,
                              void* d_out, int out_size, void* d_ws, size_t ws_size,
                              hipStream_t stream) {
    const float* x     = (const float*)d_in[0];
    const int*   ei    = (const int*)d_in[1];  // [2,E]: src = ei, dst = ei+E
    const int*   batch = (const int*)d_in[2];
    const float* W1    = (const float*)d_in[3];
    const float* b1    = (const float*)d_in[4];
    const float* W2    = (const float*)d_in[5];
    const float* b2    = (const float*)d_in[6];
    const float* linW  = (const float*)d_in[7];
    const float* linb  = (const float*)d_in[8];
    float* out = (float*)d_out;

    const int N = NNODES, E = NEDGES;
    const int* src = ei;
    const int* dst = ei + E;

    char* ws = (char*)d_ws;
    uint*  bufA16 = (uint*)ws;     ws += (size_t)N * 64 * 4;   // msg1 (fp16), 25.6MB
    uint*  bufH16 = (uint*)ws;     ws += (size_t)N * 64 * 4;   // msg2 (fp16), 25.6MB
    float* dinv   = (float*)ws;    ws += (size_t)N * 4;
    int2*  nr     = (int2*)ws;     ws += (size_t)N * 8;        // per-node (start,end)
    int*   csr    = (int*)ws;      ws += (size_t)NB * CAP * 4; // 12.8MB bucket frames
    int*   bcur   = (int*)ws;      ws += NB * 4;               // zero region
    int*   gstart = (int*)ws;      ws += NGRAPHS * 4;
    int*   gend   = (int*)ws;      ws += NGRAPHS * 4;
    short8v* wf1  = (short8v*)ws;  ws += 2048 * 16;            // fragment-ordered W1 (32KB)
    short8v* wf2  = (short8v*)ws;  ws += 2048 * 16;            // fragment-ordered W2 (32KB)
    float* pA     = (float*)ws;    ws += (size_t)NAB * 128 * 4;  // 12.8MB
    float* pB     = (float*)ws;    ws += (size_t)NAB * 128 * 4;  // 12.8MB
    // pairs aliases bufH16 (12.8MB < 25.6MB): CSR build completes before msg2 written
    uint*  pairs  = (uint*)bufH16;

    const int B = 256;

    // setup: zero(4) + prepw(2) + bounds(391) = 397 blocks
    k_setup<<<397, B, 0, stream>>>(bcur, W1, W2, wf1, wf2, batch, gstart, gend);

    // CSR build
    k_bscatter<<<(E + 4095) / 4096, B, 0, stream>>>(src, dst, bcur, pairs, E);
    k_build<<<NB, B, 0, stream>>>(pairs, bcur, nr, dinv, csr, N);

    const int gemmGrid = (N + 63) / 64;

    // layer 1 GEMM: msg1 = (x @ W1) * dinv
    k_gemm_f32<<<gemmGrid, B, 0, stream>>>(x, wf1, dinv, (ushort*)bufA16, N);

    // fused agg1 + GEMM2: msg2 = (relu(agg(msg1)+b1) @ W2) * dinv
    k_agg_gemm<<<gemmGrid, B, 0, stream>>>(bufA16, dinv, nr, csr, b1, wf2,
                                           (ushort*)bufH16, N);

    // fused agg2 + pool: per-block partial sums of h2
    k_agg_pool<<<NAB, B, 0, stream>>>(bufH16, dinv, nr, csr, batch, pA, pB);

    // per-graph reduce + head
    k_final<<<NGRAPHS, 512, 0, stream>>>(pA, pB, batch, gstart, gend, b2, linW, linb, out);
}

// Round 18
// 205.985 us; speedup vs baseline: 1.6363x; 1.0014x over previous
//
#include <hip/hip_runtime.h>
#include <hip/hip_fp16.h>
#include <cstdint>
#include <cstddef>

#define NNODES 100000
#define NEDGES 1600000
#define NGRAPHS 64
#define BSHIFT 7
#define BRANGE 128
#define NB 782   // ceil(NNODES / 128)
#define CAP 4096 // edges per bucket frame (mean 2046, sd 45 -> >40 sigma headroom)
#define NZ NB    // ints to zero (bcur)
#define LP 136   // LDS row pitch in shorts (272B: 16B-aligned, 2-way max bank alias)
#define NAB 25000 // agg2/pool blocks (N/4)

typedef short short8v __attribute__((ext_vector_type(8)));
typedef float float4v __attribute__((ext_vector_type(4)));

__device__ inline short f2h_s(float f) {
    __half h = __float2half(f);
    return __builtin_bit_cast(short, h);
}
__device__ inline ushort f2h_u(float f) {
    __half h = __float2half(f);
    return __builtin_bit_cast(ushort, h);
}
__device__ inline __half2 u2h2(uint u) { return __builtin_bit_cast(__half2, u); }
__device__ inline uint h22u(__half2 h) { return __builtin_bit_cast(uint, h); }

// ---------------- setup: zero ∪ prepw ∪ bounds (block-range partitioned) ----------------

__global__ __launch_bounds__(256) void k_setup(int* __restrict__ zb,
                                               const float* __restrict__ W1,
                                               const float* __restrict__ W2,
                                               short8v* __restrict__ o1,
                                               short8v* __restrict__ o2,
                                               const int* __restrict__ batch,
                                               int* __restrict__ gstart,
                                               int* __restrict__ gend) {
    int b = blockIdx.x, t = threadIdx.x;
    if (b < 4) {
        int i = b * 256 + t;
        if (i < NZ) zb[i] = 0;
    } else if (b < 6) {
        const float* W = (b == 5) ? W2 : W1;
        short8v* o = (b == 5) ? o2 : o1;
        for (int s = t; s < 2048; s += 256) {
            int p = s >> 6, l = s & 63;
            int kb = (p >> 3) * 32 + ((l >> 4) * 8);
            int j = (p & 7) * 16 + (l & 15);
            short8v v;
            #pragma unroll
            for (int i = 0; i < 8; ++i)
                v[i] = f2h_s(W[(size_t)(kb + i) * 128 + j]);
            o[s] = v;
        }
    } else {
        int i = (b - 6) * 256 + t;
        if (i < NNODES) {
            int bb = batch[i];
            if (i == 0 || batch[i - 1] != bb) gstart[bb] = i;
            if (i == NNODES - 1 || batch[i + 1] != bb) gend[bb] = i + 1;
        }
    }
}

// ---------------- P1: bucket scatter, 4096 edges/block, direct atomic reservation ----------------

#define P1_EPT 16
__global__ __launch_bounds__(256) void k_bscatter(const int* __restrict__ src,
                                                  const int* __restrict__ dst,
                                                  int* __restrict__ bcur,
                                                  uint* __restrict__ pairs, int E) {
    __shared__ int h[NB];
    __shared__ int base[NB];
    int t = threadIdx.x;
    long long c0 = (long long)blockIdx.x * 4096;
    if (c0 >= E) return;
    for (int i = t; i < NB; i += 256) h[i] = 0;
    __syncthreads();
    int myb[P1_EPT], mylp[P1_EPT];
    uint myv[P1_EPT];
    #pragma unroll
    for (int k = 0; k < P1_EPT; ++k) {
        long long e = c0 + t + k * 256;
        if (e < E) {
            int d = dst[e];
            myv[k] = (uint)src[e] | ((uint)(d & (BRANGE - 1)) << 24);
            myb[k] = d >> BSHIFT;
            mylp[k] = atomicAdd(&h[myb[k]], 1);
        } else myb[k] = -1;
    }
    __syncthreads();
    for (int i = t; i < NB; i += 256)
        base[i] = h[i] ? atomicAdd(&bcur[i], h[i]) : 0;
    __syncthreads();
    #pragma unroll
    for (int k = 0; k < P1_EPT; ++k)
        if (myb[k] >= 0) {
            int pos = base[myb[k]] + mylp[k];
            if (pos < CAP)
                pairs[(size_t)myb[k] * CAP + pos] = myv[k];
        }
}

// ---------------- fused per-bucket: histogram -> dinv + node ranges -> CSR scatter ----------------

__global__ __launch_bounds__(256) void k_build(const uint* __restrict__ pairs,
                                               const int* __restrict__ bcur,
                                               int2* __restrict__ nr,
                                               float* __restrict__ dinv,
                                               int* __restrict__ csr, int N) {
    __shared__ int h[256];
    __shared__ int sh[256];
    __shared__ int cur[BRANGE];
    int b = blockIdx.x, t = threadIdx.x;
    h[t] = 0;
    __syncthreads();
    const int p0 = b * CAP;
    const int cntb = min(bcur[b], CAP);
    for (int p = t; p < cntb; p += 256)
        atomicAdd(&h[pairs[p0 + p] >> 24], 1);
    __syncthreads();
    int myh = h[t];
    sh[t] = myh;
    __syncthreads();
    #pragma unroll
    for (int d = 1; d < 256; d <<= 1) {
        int val = (t >= d) ? sh[t - d] : 0;
        __syncthreads();
        sh[t] += val;
        __syncthreads();
    }
    int excl = sh[t] - myh;
    int node = (b << BSHIFT) + t;
    if (t < BRANGE) {
        cur[t] = p0 + excl;
        if (node < N) {
            nr[node] = make_int2(p0 + excl, p0 + excl + myh);
            dinv[node] = rsqrtf((float)(myh + 1));
        }
    }
    __syncthreads();
    for (int p = t; p < cntb; p += 256) {
        uint pr = pairs[p0 + p];
        int pos = atomicAdd(&cur[pr >> 24], 1);
        csr[pos] = (int)(pr & 0x00FFFFFFu);
    }
}

// ---------------- GEMM1 (f32 in): msg1[n,128] = (X @ W1) * dinv[row], fp16 out ----------------

__global__ __launch_bounds__(256) void k_gemm_f32(const float* __restrict__ X,
                                                  const short8v* __restrict__ wf,
                                                  const float* __restrict__ dinv,
                                                  ushort* __restrict__ Y, int nrows) {
    __shared__ short8v sW[2048];
    const int tid = threadIdx.x;
    const int lane = tid & 63;
    const int w = tid >> 6;

    for (int s = tid; s < 2048; s += 256) sW[s] = wf[s];
    __syncthreads();

    const int row0 = blockIdx.x * 64 + w * 16;
    const int arow = row0 + (lane & 15);
    float4v acc[8];
    #pragma unroll
    for (int ct = 0; ct < 8; ++ct) acc[ct] = (float4v)0.f;

    #pragma unroll
    for (int kk = 0; kk < 4; ++kk) {
        short8v a = (short8v)0;
        if (arow < nrows) {
            const float* xp = X + (size_t)arow * 128 + kk * 32 + ((lane >> 4) * 8);
            float4 f0 = ((const float4*)xp)[0];
            float4 f1 = ((const float4*)xp)[1];
            a[0] = f2h_s(f0.x); a[1] = f2h_s(f0.y);
            a[2] = f2h_s(f0.z); a[3] = f2h_s(f0.w);
            a[4] = f2h_s(f1.x); a[5] = f2h_s(f1.y);
            a[6] = f2h_s(f1.z); a[7] = f2h_s(f1.w);
        }
        #pragma unroll
        for (int ct = 0; ct < 8; ++ct)
            acc[ct] = __builtin_amdgcn_mfma_f32_16x16x32_f16(a, sW[(kk * 8 + ct) * 64 + lane],
                                                             acc[ct], 0, 0, 0);
    }

    const int orow = row0 + ((lane >> 4) << 2);
    #pragma unroll
    for (int r = 0; r < 4; ++r) {
        int row = orow + r;
        if (row < nrows) {
            float dr = dinv[row];
            #pragma unroll
            for (int ct = 0; ct < 8; ++ct)
                Y[(size_t)row * 128 + ct * 16 + (lane & 15)] = f2h_u(acc[ct][r] * dr);
        }
    }
}

// ---------------- FUSED agg1 + GEMM2 ----------------

__global__ __launch_bounds__(256, 8) void k_agg_gemm(const uint* __restrict__ msg,
                                                     const float* __restrict__ dinv,
                                                     const int2* __restrict__ nr,
                                                     const int* __restrict__ csr,
                                                     const float* __restrict__ bias,
                                                     const short8v* __restrict__ wf,
                                                     ushort* __restrict__ Y, int n) {
    __shared__ ushort ht[64 * LP];  // 17.4 KB
    const int t = threadIdx.x;
    const int lane = t & 63;
    const int w = t >> 6;
    const int row0 = blockIdx.x * 64;
    const float bx = bias[lane * 2];
    const float by = bias[lane * 2 + 1];

    // phase 1: aggregate 16 nodes per wave
    for (int i = 0; i < 16; ++i) {
        const int r = w * 16 + i;
        const int wid = row0 + r;
        uint o = 0u;
        if (wid < n) {
            __half2 a0 = u2h2(msg[(size_t)wid * 64 + lane]);
            __half2 a1 = u2h2(0u), a2 = u2h2(0u);
            const int2 rg = nr[wid];
            const int e0 = rg.x, e1 = rg.y;
            for (int e = e0; e < e1; e += 64) {
                int me = e + lane;
                int sidx = (me < e1) ? csr[me] : 0;
                int cnt = min(64, e1 - e);
                for (int kb = 0; kb < cnt; kb += 6) {
                    int lim = cnt - 1;
                    int s0 = __shfl(sidx, min(kb + 0, lim));
                    int s1 = __shfl(sidx, min(kb + 1, lim));
                    int s2 = __shfl(sidx, min(kb + 2, lim));
                    int s3 = __shfl(sidx, min(kb + 3, lim));
                    int s4 = __shfl(sidx, min(kb + 4, lim));
                    int s5 = __shfl(sidx, min(kb + 5, lim));
                    uint u0 = msg[(size_t)s0 * 64 + lane];
                    uint u1 = msg[(size_t)s1 * 64 + lane];
                    uint u2 = msg[(size_t)s2 * 64 + lane];
                    uint u3 = msg[(size_t)s3 * 64 + lane];
                    uint u4 = msg[(size_t)s4 * 64 + lane];
                    uint u5 = msg[(size_t)s5 * 64 + lane];
                    u1 = (kb + 1 < cnt) ? u1 : 0u;
                    u2 = (kb + 2 < cnt) ? u2 : 0u;
                    u3 = (kb + 3 < cnt) ? u3 : 0u;
                    u4 = (kb + 4 < cnt) ? u4 : 0u;
                    u5 = (kb + 5 < cnt) ? u5 : 0u;
                    a0 = __hadd2(a0, u2h2(u0));
                    a1 = __hadd2(a1, u2h2(u1));
                    a2 = __hadd2(a2, u2h2(u2));
                    a0 = __hadd2(a0, u2h2(u3));
                    a1 = __hadd2(a1, u2h2(u4));
                    a2 = __hadd2(a2, u2h2(u5));
                }
            }
            __half2 acc = __hadd2(__hadd2(a0, a1), a2);
            float2 f = __half22float2(acc);
            float dd = dinv[wid];
            float ax = fmaxf(f.x * dd + bx, 0.f);
            float ay = fmaxf(f.y * dd + by, 0.f);
            o = h22u(__floats2half2_rn(ax, ay));
        }
        *(uint*)&ht[r * LP + lane * 2] = o;
    }
    __syncthreads();

    // phase 2: GEMM on the 64x128 LDS tile; W2 fragments from global (L2-hot)
    float4v acc[8];
    #pragma unroll
    for (int ct = 0; ct < 8; ++ct) acc[ct] = (float4v)0.f;
    const int arow = w * 16 + (lane & 15);
    #pragma unroll 1
    for (int kk = 0; kk < 4; ++kk) {
        short8v a = *(const short8v*)&ht[arow * LP + kk * 32 + ((lane >> 4) * 8)];
        #pragma unroll
        for (int ct = 0; ct < 8; ++ct)
            acc[ct] = __builtin_amdgcn_mfma_f32_16x16x32_f16(a, wf[(kk * 8 + ct) * 64 + lane],
                                                             acc[ct], 0, 0, 0);
    }
    const int orow = row0 + w * 16 + ((lane >> 4) << 2);
    #pragma unroll
    for (int r = 0; r < 4; ++r) {
        int row = orow + r;
        if (row < n) {
            float dr = dinv[row];
            #pragma unroll
            for (int ct = 0; ct < 8; ++ct)
                Y[(size_t)row * 128 + ct * 16 + (lane & 15)] = f2h_u(acc[ct][r] * dr);
        }
    }
}

// ---------------- FUSED agg2 + pool: per-block (4 nodes) partial sums, A/B by graph ----------------

__global__ __launch_bounds__(256) void k_agg_pool(const uint* __restrict__ msg,
                                                  const float* __restrict__ dinv,
                                                  const int2* __restrict__ nr,
                                                  const int* __restrict__ csr,
                                                  const int* __restrict__ batch,
                                                  float* __restrict__ pA,
                                                  float* __restrict__ pB) {
    __shared__ float red[4][128];
    __shared__ int selw[4];
    const int blk = blockIdx.x;
    const int t = threadIdx.x;
    const int lane = t & 63;
    const int w = t >> 6;
    const int wid = blk * 4 + w;  // N % 4 == 0, always valid

    __half2 a0 = u2h2(msg[(size_t)wid * 64 + lane]);
    __half2 a1 = u2h2(0u), a2 = u2h2(0u);
    const int2 rg = nr[wid];
    const int e0 = rg.x, e1 = rg.y;
    for (int e = e0; e < e1; e += 64) {
        int me = e + lane;
        int sidx = (me < e1) ? csr[me] : 0;
        int cnt = min(64, e1 - e);
        for (int kb = 0; kb < cnt; kb += 6) {
            int lim = cnt - 1;
            int s0 = __shfl(sidx, min(kb + 0, lim));
            int s1 = __shfl(sidx, min(kb + 1, lim));
            int s2 = __shfl(sidx, min(kb + 2, lim));
            int s3 = __shfl(sidx, min(kb + 3, lim));
            int s4 = __shfl(sidx, min(kb + 4, lim));
            int s5 = __shfl(sidx, min(kb + 5, lim));
            uint u0 = msg[(size_t)s0 * 64 + lane];
            uint u1 = msg[(size_t)s1 * 64 + lane];
            uint u2 = msg[(size_t)s2 * 64 + lane];
            uint u3 = msg[(size_t)s3 * 64 + lane];
            uint u4 = msg[(size_t)s4 * 64 + lane];
            uint u5 = msg[(size_t)s5 * 64 + lane];
            u1 = (kb + 1 < cnt) ? u1 : 0u;
            u2 = (kb + 2 < cnt) ? u2 : 0u;
            u3 = (kb + 3 < cnt) ? u3 : 0u;
            u4 = (kb + 4 < cnt) ? u4 : 0u;
            u5 = (kb + 5 < cnt) ? u5 : 0u;
            a0 = __hadd2(a0, u2h2(u0));
            a1 = __hadd2(a1, u2h2(u1));
            a2 = __hadd2(a2, u2h2(u2));
            a0 = __hadd2(a0, u2h2(u3));
            a1 = __hadd2(a1, u2h2(u4));
            a2 = __hadd2(a2, u2h2(u5));
        }
    }
    __half2 acc = __hadd2(__hadd2(a0, a1), a2);
    float2 f = __half22float2(acc);
    float dd = dinv[wid];
    red[w][lane * 2] = f.x * dd;
    red[w][lane * 2 + 1] = f.y * dd;
    if (lane == 0) selw[w] = (batch[wid] != batch[blk * 4]) ? 1 : 0;
    __syncthreads();
    if (t < 128) {
        float a = 0.f, b = 0.f;
        #pragma unroll
        for (int ww = 0; ww < 4; ++ww) {
            float v = red[ww][t];
            if (selw[ww]) b += v; else a += v;
        }
        pA[(size_t)blk * 128 + t] = a;
        if (selw[0] | selw[1] | selw[2] | selw[3])
            pB[(size_t)blk * 128 + t] = b;
    }
}

// ---------------- final: per-graph reduce (512 threads, 4-way strided) + linear head ----------------

__global__ __launch_bounds__(512) void k_final(const float* __restrict__ pA,
                                               const float* __restrict__ pB,
                                               const int* __restrict__ batch,
                                               const int* __restrict__ gstart,
                                               const int* __restrict__ gend,
                                               const float* __restrict__ b2,
                                               const float* __restrict__ linW,
                                               const float* __restrict__ linb,
                                               float* __restrict__ out) {
    __shared__ float sq[4][128];
    __shared__ float red[128][8];
    int g = blockIdx.x;
    int t = threadIdx.x;
    int c = t & 127;   // channel
    int q = t >> 7;    // quarter 0..3
    int b0 = gstart[g] >> 2;
    int b1 = (gend[g] - 1) >> 2;
    float v = 0.f;
    #pragma unroll 4
    for (int b = b0 + 1 + q; b <= b1; b += 4)
        v += pA[(size_t)b * 128 + c];
    if (q == 0)
        v += ((batch[b0 * 4] != g) ? pB : pA)[(size_t)b0 * 128 + c];
    sq[q][c] = v;
    __syncthreads();
    if (t < 128) {
        float sv = sq[0][t] + sq[1][t] + sq[2][t] + sq[3][t];
        float cnt = (float)(gend[g] - gstart[g]);
        sv = sv / fmaxf(cnt, 1.0f) + b2[t];
        #pragma unroll
        for (int k = 0; k < 8; ++k) red[t][k] = sv * linW[(size_t)t * 8 + k];
    }
    __syncthreads();
    #pragma unroll
    for (int st = 64; st > 0; st >>= 1) {
        if (t < st) {
            #pragma unroll
            for (int k = 0; k < 8; ++k) red[t][k] += red[t + st][k];
        }
        __syncthreads();
    }
    if (t < 8) out[(size_t)g * 8 + t] = red[0][t] + linb[t];
}

// ---------------- launch ----------------

extern "C" void kernel_launch(void* const* d_in, const int* in_sizes, int n_in,
                              void* d_out, int out_size, void* d_ws, size_t ws_size,
                              hipStream_t stream) {
    const float* x     = (const float*)d_in[0];
    const int*   ei    = (const int*)d_in[1];  // [2,E]: src = ei, dst = ei+E
    const int*   batch = (const int*)d_in[2];
    const float* W1    = (const float*)d_in[3];
    const float* b1    = (const float*)d_in[4];
    const float* W2    = (const float*)d_in[5];
    const float* b2    = (const float*)d_in[6];
    const float* linW  = (const float*)d_in[7];
    const float* linb  = (const float*)d_in[8];
    float* out = (float*)d_out;

    const int N = NNODES, E = NEDGES;
    const int* src = ei;
    const int* dst = ei + E;

    char* ws = (char*)d_ws;
    uint*  bufA16 = (uint*)ws;     ws += (size_t)N * 64 * 4;   // msg1 (fp16), 25.6MB
    uint*  bufH16 = (uint*)ws;     ws += (size_t)N * 64 * 4;   // msg2 (fp16), 25.6MB
    float* dinv   = (float*)ws;    ws += (size_t)N * 4;
    int2*  nr     = (int2*)ws;     ws += (size_t)N * 8;        // per-node (start,end)
    int*   csr    = (int*)ws;      ws += (size_t)NB * CAP * 4; // 12.8MB bucket frames
    int*   bcur   = (int*)ws;      ws += NB * 4;               // zero region
    int*   gstart = (int*)ws;      ws += NGRAPHS * 4;
    int*   gend   = (int*)ws;      ws += NGRAPHS * 4;
    short8v* wf1  = (short8v*)ws;  ws += 2048 * 16;            // fragment-ordered W1 (32KB)
    short8v* wf2  = (short8v*)ws;  ws += 2048 * 16;            // fragment-ordered W2 (32KB)
    float* pA     = (float*)ws;    ws += (size_t)NAB * 128 * 4;  // 12.8MB
    float* pB     = (float*)ws;    ws += (size_t)NAB * 128 * 4;  // 12.8MB
    // pairs aliases bufH16 (12.8MB < 25.6MB): CSR build completes before msg2 written
    uint*  pairs  = (uint*)bufH16;

    const int B = 256;

    // setup: zero(4) + prepw(2) + bounds(391) = 397 blocks
    k_setup<<<397, B, 0, stream>>>(bcur, W1, W2, wf1, wf2, batch, gstart, gend);

    // CSR build
    k_bscatter<<<(E + 4095) / 4096, B, 0, stream>>>(src, dst, bcur, pairs, E);
    k_build<<<NB, B, 0, stream>>>(pairs, bcur, nr, dinv, csr, N);

    const int gemmGrid = (N + 63) / 64;

    // layer 1 GEMM: msg1 = (x @ W1) * dinv
    k_gemm_f32<<<gemmGrid, B, 0, stream>>>(x, wf1, dinv, (ushort*)bufA16, N);

    // fused agg1 + GEMM2: msg2 = (relu(agg(msg1)+b1) @ W2) * dinv
    k_agg_gemm<<<gemmGrid, B, 0, stream>>>(bufA16, dinv, nr, csr, b1, wf2,
                                           (ushort*)bufH16, N);

    // fused agg2 + pool: per-block partial sums of h2
    k_agg_pool<<<NAB, B, 0, stream>>>(bufH16, dinv, nr, csr, batch, pA, pB);

    // per-graph reduce + head
    k_final<<<NGRAPHS, 512, 0, stream>>>(pA, pB, batch, gstart, gend, b2, linW, linb, out);
}

// Round 19
// 205.218 us; speedup vs baseline: 1.6424x; 1.0037x over previous
//
#include <hip/hip_runtime.h>
#include <hip/hip_fp16.h>
#include <cstdint>
#include <cstddef>

#define NNODES 100000
#define NEDGES 1600000
#define NGRAPHS 64
#define BSHIFT 7
#define BRANGE 128
#define NB 782   // ceil(NNODES / 128)
#define CAP 4096 // edges per bucket frame (mean 2046, sd 45 -> >40 sigma headroom)
#define NZ NB    // ints to zero (bcur)
#define LP 136   // LDS row pitch in shorts (272B: 16B-aligned)
#define NAB 25000 // agg2/pool blocks (N/4)

typedef short short8v __attribute__((ext_vector_type(8)));
typedef float float4v __attribute__((ext_vector_type(4)));

__device__ inline short f2h_s(float f) {
    __half h = __float2half(f);
    return __builtin_bit_cast(short, h);
}
__device__ inline ushort f2h_u(float f) {
    __half h = __float2half(f);
    return __builtin_bit_cast(ushort, h);
}
__device__ inline __half2 u2h2(uint u) { return __builtin_bit_cast(__half2, u); }
__device__ inline uint h22u(__half2 h) { return __builtin_bit_cast(uint, h); }

// ---------------- setup: zero ∪ prepw ∪ bounds (block-range partitioned) ----------------

__global__ __launch_bounds__(256) void k_setup(int* __restrict__ zb,
                                               const float* __restrict__ W1,
                                               const float* __restrict__ W2,
                                               short8v* __restrict__ o1,
                                               short8v* __restrict__ o2,
                                               const int* __restrict__ batch,
                                               int* __restrict__ gstart,
                                               int* __restrict__ gend) {
    int b = blockIdx.x, t = threadIdx.x;
    if (b < 4) {
        int i = b * 256 + t;
        if (i < NZ) zb[i] = 0;
    } else if (b < 6) {
        const float* W = (b == 5) ? W2 : W1;
        short8v* o = (b == 5) ? o2 : o1;
        for (int s = t; s < 2048; s += 256) {
            int p = s >> 6, l = s & 63;
            int kb = (p >> 3) * 32 + ((l >> 4) * 8);
            int j = (p & 7) * 16 + (l & 15);
            short8v v;
            #pragma unroll
            for (int i = 0; i < 8; ++i)
                v[i] = f2h_s(W[(size_t)(kb + i) * 128 + j]);
            o[s] = v;
        }
    } else {
        int i = (b - 6) * 256 + t;
        if (i < NNODES) {
            int bb = batch[i];
            if (i == 0 || batch[i - 1] != bb) gstart[bb] = i;
            if (i == NNODES - 1 || batch[i + 1] != bb) gend[bb] = i + 1;
        }
    }
}

// ---------------- P1: bucket scatter, 4096 edges/block, direct atomic reservation ----------------

#define P1_EPT 16
__global__ __launch_bounds__(256) void k_bscatter(const int* __restrict__ src,
                                                  const int* __restrict__ dst,
                                                  int* __restrict__ bcur,
                                                  uint* __restrict__ pairs, int E) {
    __shared__ int h[NB];
    __shared__ int base[NB];
    int t = threadIdx.x;
    long long c0 = (long long)blockIdx.x * 4096;
    if (c0 >= E) return;
    for (int i = t; i < NB; i += 256) h[i] = 0;
    __syncthreads();
    int myb[P1_EPT], mylp[P1_EPT];
    uint myv[P1_EPT];
    #pragma unroll
    for (int k = 0; k < P1_EPT; ++k) {
        long long e = c0 + t + k * 256;
        if (e < E) {
            int d = dst[e];
            myv[k] = (uint)src[e] | ((uint)(d & (BRANGE - 1)) << 24);
            myb[k] = d >> BSHIFT;
            mylp[k] = atomicAdd(&h[myb[k]], 1);
        } else myb[k] = -1;
    }
    __syncthreads();
    for (int i = t; i < NB; i += 256)
        base[i] = h[i] ? atomicAdd(&bcur[i], h[i]) : 0;
    __syncthreads();
    #pragma unroll
    for (int k = 0; k < P1_EPT; ++k)
        if (myb[k] >= 0) {
            int pos = base[myb[k]] + mylp[k];
            if (pos < CAP)
                pairs[(size_t)myb[k] * CAP + pos] = myv[k];
        }
}

// ---------------- fused per-bucket: histogram -> dinv + node ranges -> CSR scatter ----------------

__global__ __launch_bounds__(256) void k_build(const uint* __restrict__ pairs,
                                               const int* __restrict__ bcur,
                                               int2* __restrict__ nr,
                                               float* __restrict__ dinv,
                                               int* __restrict__ csr, int N) {
    __shared__ int h[256];
    __shared__ int sh[256];
    __shared__ int cur[BRANGE];
    int b = blockIdx.x, t = threadIdx.x;
    h[t] = 0;
    __syncthreads();
    const int p0 = b * CAP;
    const int cntb = min(bcur[b], CAP);
    for (int p = t; p < cntb; p += 256)
        atomicAdd(&h[pairs[p0 + p] >> 24], 1);
    __syncthreads();
    int myh = h[t];
    sh[t] = myh;
    __syncthreads();
    #pragma unroll
    for (int d = 1; d < 256; d <<= 1) {
        int val = (t >= d) ? sh[t - d] : 0;
        __syncthreads();
        sh[t] += val;
        __syncthreads();
    }
    int excl = sh[t] - myh;
    int node = (b << BSHIFT) + t;
    if (t < BRANGE) {
        cur[t] = p0 + excl;
        if (node < N) {
            nr[node] = make_int2(p0 + excl, p0 + excl + myh);
            dinv[node] = rsqrtf((float)(myh + 1));
        }
    }
    __syncthreads();
    for (int p = t; p < cntb; p += 256) {
        uint pr = pairs[p0 + p];
        int pos = atomicAdd(&cur[pr >> 24], 1);
        csr[pos] = (int)(pr & 0x00FFFFFFu);
    }
}

// ---------------- GEMM1 (f32 in): msg1[n,128] = (X @ W1) * dinv[row], fp16 out ----------------

__global__ __launch_bounds__(256) void k_gemm_f32(const float* __restrict__ X,
                                                  const short8v* __restrict__ wf,
                                                  const float* __restrict__ dinv,
                                                  ushort* __restrict__ Y, int nrows) {
    __shared__ short8v sW[2048];
    const int tid = threadIdx.x;
    const int lane = tid & 63;
    const int w = tid >> 6;

    for (int s = tid; s < 2048; s += 256) sW[s] = wf[s];
    __syncthreads();

    const int row0 = blockIdx.x * 64 + w * 16;
    const int arow = row0 + (lane & 15);
    float4v acc[8];
    #pragma unroll
    for (int ct = 0; ct < 8; ++ct) acc[ct] = (float4v)0.f;

    #pragma unroll
    for (int kk = 0; kk < 4; ++kk) {
        short8v a = (short8v)0;
        if (arow < nrows) {
            const float* xp = X + (size_t)arow * 128 + kk * 32 + ((lane >> 4) * 8);
            float4 f0 = ((const float4*)xp)[0];
            float4 f1 = ((const float4*)xp)[1];
            a[0] = f2h_s(f0.x); a[1] = f2h_s(f0.y);
            a[2] = f2h_s(f0.z); a[3] = f2h_s(f0.w);
            a[4] = f2h_s(f1.x); a[5] = f2h_s(f1.y);
            a[6] = f2h_s(f1.z); a[7] = f2h_s(f1.w);
        }
        #pragma unroll
        for (int ct = 0; ct < 8; ++ct)
            acc[ct] = __builtin_amdgcn_mfma_f32_16x16x32_f16(a, sW[(kk * 8 + ct) * 64 + lane],
                                                             acc[ct], 0, 0, 0);
    }

    const int orow = row0 + ((lane >> 4) << 2);
    #pragma unroll
    for (int r = 0; r < 4; ++r) {
        int row = orow + r;
        if (row < nrows) {
            float dr = dinv[row];
            #pragma unroll
            for (int ct = 0; ct < 8; ++ct)
                Y[(size_t)row * 128 + ct * 16 + (lane & 15)] = f2h_u(acc[ct][r] * dr);
        }
    }
}

// ---------------- FUSED agg1 + GEMM2, wave-private LDS, NO BARRIER ----------------
// Each wave aggregates 16 nodes into its own LDS region, then immediately GEMMs
// those 16 rows (A from its LDS, W2 fragments from global/L2). No cross-wave deps.

__global__ __launch_bounds__(256, 8) void k_agg_gemm(const uint* __restrict__ msg,
                                                     const float* __restrict__ dinv,
                                                     const int2* __restrict__ nr,
                                                     const int* __restrict__ csr,
                                                     const float* __restrict__ bias,
                                                     const short8v* __restrict__ wf,
                                                     ushort* __restrict__ Y, int n) {
    __shared__ ushort ht[4][16 * LP];  // per-wave 4.35 KB regions, 17.4 KB total
    const int t = threadIdx.x;
    const int lane = t & 63;
    const int w = t >> 6;
    const int row0 = blockIdx.x * 64;
    ushort* myht = ht[w];
    const float bx = bias[lane * 2];
    const float by = bias[lane * 2 + 1];

    // phase 1 (per wave): aggregate 16 nodes into wave-private LDS
    for (int i = 0; i < 16; ++i) {
        const int wid = row0 + w * 16 + i;
        uint o = 0u;
        if (wid < n) {
            __half2 a0 = u2h2(msg[(size_t)wid * 64 + lane]);
            __half2 a1 = u2h2(0u), a2 = u2h2(0u);
            const int2 rg = nr[wid];
            const int e0 = rg.x, e1 = rg.y;
            for (int e = e0; e < e1; e += 64) {
                int me = e + lane;
                int sidx = (me < e1) ? csr[me] : 0;
                int cnt = min(64, e1 - e);
                for (int kb = 0; kb < cnt; kb += 6) {
                    int lim = cnt - 1;
                    int s0 = __shfl(sidx, min(kb + 0, lim));
                    int s1 = __shfl(sidx, min(kb + 1, lim));
                    int s2 = __shfl(sidx, min(kb + 2, lim));
                    int s3 = __shfl(sidx, min(kb + 3, lim));
                    int s4 = __shfl(sidx, min(kb + 4, lim));
                    int s5 = __shfl(sidx, min(kb + 5, lim));
                    uint u0 = msg[(size_t)s0 * 64 + lane];
                    uint u1 = msg[(size_t)s1 * 64 + lane];
                    uint u2 = msg[(size_t)s2 * 64 + lane];
                    uint u3 = msg[(size_t)s3 * 64 + lane];
                    uint u4 = msg[(size_t)s4 * 64 + lane];
                    uint u5 = msg[(size_t)s5 * 64 + lane];
                    u1 = (kb + 1 < cnt) ? u1 : 0u;
                    u2 = (kb + 2 < cnt) ? u2 : 0u;
                    u3 = (kb + 3 < cnt) ? u3 : 0u;
                    u4 = (kb + 4 < cnt) ? u4 : 0u;
                    u5 = (kb + 5 < cnt) ? u5 : 0u;
                    a0 = __hadd2(a0, u2h2(u0));
                    a1 = __hadd2(a1, u2h2(u1));
                    a2 = __hadd2(a2, u2h2(u2));
                    a0 = __hadd2(a0, u2h2(u3));
                    a1 = __hadd2(a1, u2h2(u4));
                    a2 = __hadd2(a2, u2h2(u5));
                }
            }
            __half2 acc = __hadd2(__hadd2(a0, a1), a2);
            float2 f = __half22float2(acc);
            float dd = dinv[wid];
            float ax = fmaxf(f.x * dd + bx, 0.f);
            float ay = fmaxf(f.y * dd + by, 0.f);
            o = h22u(__floats2half2_rn(ax, ay));
        }
        *(uint*)&myht[i * LP + lane * 2] = o;
    }
    // no __syncthreads: LDS region is wave-private; in-wave lgkmcnt ordering suffices

    // phase 2 (per wave): GEMM its own 16 rows; W2 fragments from global (L2-hot)
    float4v acc[8];
    #pragma unroll
    for (int ct = 0; ct < 8; ++ct) acc[ct] = (float4v)0.f;
    const int arow = lane & 15;
    #pragma unroll 1
    for (int kk = 0; kk < 4; ++kk) {
        short8v a = *(const short8v*)&myht[arow * LP + kk * 32 + ((lane >> 4) * 8)];
        #pragma unroll
        for (int ct = 0; ct < 8; ++ct)
            acc[ct] = __builtin_amdgcn_mfma_f32_16x16x32_f16(a, wf[(kk * 8 + ct) * 64 + lane],
                                                             acc[ct], 0, 0, 0);
    }
    const int orow = row0 + w * 16 + ((lane >> 4) << 2);
    #pragma unroll
    for (int r = 0; r < 4; ++r) {
        int row = orow + r;
        if (row < n) {
            float dr = dinv[row];
            #pragma unroll
            for (int ct = 0; ct < 8; ++ct)
                Y[(size_t)row * 128 + ct * 16 + (lane & 15)] = f2h_u(acc[ct][r] * dr);
        }
    }
}

// ---------------- FUSED agg2 + pool: per-block (4 nodes) partial sums, A/B by graph ----------------

__global__ __launch_bounds__(256) void k_agg_pool(const uint* __restrict__ msg,
                                                  const float* __restrict__ dinv,
                                                  const int2* __restrict__ nr,
                                                  const int* __restrict__ csr,
                                                  const int* __restrict__ batch,
                                                  float* __restrict__ pA,
                                                  float* __restrict__ pB) {
    __shared__ float red[4][128];
    __shared__ int selw[4];
    const int blk = blockIdx.x;
    const int t = threadIdx.x;
    const int lane = t & 63;
    const int w = t >> 6;
    const int wid = blk * 4 + w;  // N % 4 == 0, always valid

    __half2 a0 = u2h2(msg[(size_t)wid * 64 + lane]);
    __half2 a1 = u2h2(0u), a2 = u2h2(0u);
    const int2 rg = nr[wid];
    const int e0 = rg.x, e1 = rg.y;
    for (int e = e0; e < e1; e += 64) {
        int me = e + lane;
        int sidx = (me < e1) ? csr[me] : 0;
        int cnt = min(64, e1 - e);
        for (int kb = 0; kb < cnt; kb += 6) {
            int lim = cnt - 1;
            int s0 = __shfl(sidx, min(kb + 0, lim));
            int s1 = __shfl(sidx, min(kb + 1, lim));
            int s2 = __shfl(sidx, min(kb + 2, lim));
            int s3 = __shfl(sidx, min(kb + 3, lim));
            int s4 = __shfl(sidx, min(kb + 4, lim));
            int s5 = __shfl(sidx, min(kb + 5, lim));
            uint u0 = msg[(size_t)s0 * 64 + lane];
            uint u1 = msg[(size_t)s1 * 64 + lane];
            uint u2 = msg[(size_t)s2 * 64 + lane];
            uint u3 = msg[(size_t)s3 * 64 + lane];
            uint u4 = msg[(size_t)s4 * 64 + lane];
            uint u5 = msg[(size_t)s5 * 64 + lane];
            u1 = (kb + 1 < cnt) ? u1 : 0u;
            u2 = (kb + 2 < cnt) ? u2 : 0u;
            u3 = (kb + 3 < cnt) ? u3 : 0u;
            u4 = (kb + 4 < cnt) ? u4 : 0u;
            u5 = (kb + 5 < cnt) ? u5 : 0u;
            a0 = __hadd2(a0, u2h2(u0));
            a1 = __hadd2(a1, u2h2(u1));
            a2 = __hadd2(a2, u2h2(u2));
            a0 = __hadd2(a0, u2h2(u3));
            a1 = __hadd2(a1, u2h2(u4));
            a2 = __hadd2(a2, u2h2(u5));
        }
    }
    __half2 acc = __hadd2(__hadd2(a0, a1), a2);
    float2 f = __half22float2(acc);
    float dd = dinv[wid];
    red[w][lane * 2] = f.x * dd;
    red[w][lane * 2 + 1] = f.y * dd;
    if (lane == 0) selw[w] = (batch[wid] != batch[blk * 4]) ? 1 : 0;
    __syncthreads();
    if (t < 128) {
        float a = 0.f, b = 0.f;
        #pragma unroll
        for (int ww = 0; ww < 4; ++ww) {
            float v = red[ww][t];
            if (selw[ww]) b += v; else a += v;
        }
        pA[(size_t)blk * 128 + t] = a;
        if (selw[0] | selw[1] | selw[2] | selw[3])
            pB[(size_t)blk * 128 + t] = b;
    }
}

// ---------------- final: per-graph reduce (512 threads, 4-way strided) + linear head ----------------

__global__ __launch_bounds__(512) void k_final(const float* __restrict__ pA,
                                               const float* __restrict__ pB,
                                               const int* __restrict__ batch,
                                               const int* __restrict__ gstart,
                                               const int* __restrict__ gend,
                                               const float* __restrict__ b2,
                                               const float* __restrict__ linW,
                                               const float* __restrict__ linb,
                                               float* __restrict__ out) {
    __shared__ float sq[4][128];
    __shared__ float red[128][8];
    int g = blockIdx.x;
    int t = threadIdx.x;
    int c = t & 127;   // channel
    int q = t >> 7;    // quarter 0..3
    int b0 = gstart[g] >> 2;
    int b1 = (gend[g] - 1) >> 2;
    float v = 0.f;
    #pragma unroll 4
    for (int b = b0 + 1 + q; b <= b1; b += 4)
        v += pA[(size_t)b * 128 + c];
    if (q == 0)
        v += ((batch[b0 * 4] != g) ? pB : pA)[(size_t)b0 * 128 + c];
    sq[q][c] = v;
    __syncthreads();
    if (t < 128) {
        float sv = sq[0][t] + sq[1][t] + sq[2][t] + sq[3][t];
        float cnt = (float)(gend[g] - gstart[g]);
        sv = sv / fmaxf(cnt, 1.0f) + b2[t];
        #pragma unroll
        for (int k = 0; k < 8; ++k) red[t][k] = sv * linW[(size_t)t * 8 + k];
    }
    __syncthreads();
    #pragma unroll
    for (int st = 64; st > 0; st >>= 1) {
        if (t < st) {
            #pragma unroll
            for (int k = 0; k < 8; ++k) red[t][k] += red[t + st][k];
        }
        __syncthreads();
    }
    if (t < 8) out[(size_t)g * 8 + t] = red[0][t] + linb[t];
}

// ---------------- launch ----------------

extern "C" void kernel_launch(void* const* d_in, const int* in_sizes, int n_in,
                              void* d_out, int out_size, void* d_ws, size_t ws_size,
                              hipStream_t stream) {
    const float* x     = (const float*)d_in[0];
    const int*   ei    = (const int*)d_in[1];  // [2,E]: src = ei, dst = ei+E
    const int*   batch = (const int*)d_in[2];
    const float* W1    = (const float*)d_in[3];
    const float* b1    = (const float*)d_in[4];
    const float* W2    = (const float*)d_in[5];
    const float* b2    = (const float*)d_in[6];
    const float* linW  = (const float*)d_in[7];
    const float* linb  = (const float*)d_in[8];
    float* out = (float*)d_out;

    const int N = NNODES, E = NEDGES;
    const int* src = ei;
    const int* dst = ei + E;

    char* ws = (char*)d_ws;
    uint*  bufA16 = (uint*)ws;     ws += (size_t)N * 64 * 4;   // msg1 (fp16), 25.6MB
    uint*  bufH16 = (uint*)ws;     ws += (size_t)N * 64 * 4;   // msg2 (fp16), 25.6MB
    float* dinv   = (float*)ws;    ws += (size_t)N * 4;
    int2*  nr     = (int2*)ws;     ws += (size_t)N * 8;        // per-node (start,end)
    int*   csr    = (int*)ws;      ws += (size_t)NB * CAP * 4; // 12.8MB bucket frames
    int*   bcur   = (int*)ws;      ws += NB * 4;               // zero region
    int*   gstart = (int*)ws;      ws += NGRAPHS * 4;
    int*   gend   = (int*)ws;      ws += NGRAPHS * 4;
    short8v* wf1  = (short8v*)ws;  ws += 2048 * 16;            // fragment-ordered W1 (32KB)
    short8v* wf2  = (short8v*)ws;  ws += 2048 * 16;            // fragment-ordered W2 (32KB)
    float* pA     = (float*)ws;    ws += (size_t)NAB * 128 * 4;  // 12.8MB
    float* pB     = (float*)ws;    ws += (size_t)NAB * 128 * 4;  // 12.8MB
    // pairs aliases bufH16 (12.8MB < 25.6MB): CSR build completes before msg2 written
    uint*  pairs  = (uint*)bufH16;

    const int B = 256;

    // setup: zero(4) + prepw(2) + bounds(391) = 397 blocks
    k_setup<<<397, B, 0, stream>>>(bcur, W1, W2, wf1, wf2, batch, gstart, gend);

    // CSR build
    k_bscatter<<<(E + 4095) / 4096, B, 0, stream>>>(src, dst, bcur, pairs, E);
    k_build<<<NB, B, 0, stream>>>(pairs, bcur, nr, dinv, csr, N);

    const int gemmGrid = (N + 63) / 64;

    // layer 1 GEMM: msg1 = (x @ W1) * dinv
    k_gemm_f32<<<gemmGrid, B, 0, stream>>>(x, wf1, dinv, (ushort*)bufA16, N);

    // fused agg1 + GEMM2: msg2 = (relu(agg(msg1)+b1) @ W2) * dinv
    k_agg_gemm<<<gemmGrid, B, 0, stream>>>(bufA16, dinv, nr, csr, b1, wf2,
                                           (ushort*)bufH16, N);

    // fused agg2 + pool: per-block partial sums of h2
    k_agg_pool<<<NAB, B, 0, stream>>>(bufH16, dinv, nr, csr, batch, pA, pB);

    // per-graph reduce + head
    k_final<<<NGRAPHS, 512, 0, stream>>>(pA, pB, batch, gstart, gend, b2, linW, linb, out);
}

// Round 20
// 204.479 us; speedup vs baseline: 1.6483x; 1.0036x over previous
//
#include <hip/hip_runtime.h>
#include <hip/hip_fp16.h>
#include <cstdint>
#include <cstddef>

#define NNODES 100000
#define NEDGES 1600000
#define NGRAPHS 64
#define BSHIFT 7
#define BRANGE 128
#define NB 782   // ceil(NNODES / 128)
#define CAP 4096 // edges per bucket frame (mean 2046, sd 45 -> >40 sigma headroom)
#define NZ NB    // ints to zero (bcur)
#define LP 136   // LDS row pitch in shorts (272B: 16B-aligned)
#define NAB 25000 // agg2/pool blocks (N/4)

typedef short short8v __attribute__((ext_vector_type(8)));
typedef float float4v __attribute__((ext_vector_type(4)));

__device__ inline short f2h_s(float f) {
    __half h = __float2half(f);
    return __builtin_bit_cast(short, h);
}
__device__ inline ushort f2h_u(float f) {
    __half h = __float2half(f);
    return __builtin_bit_cast(ushort, h);
}
__device__ inline __half2 u2h2(uint u) { return __builtin_bit_cast(__half2, u); }
__device__ inline uint h22u(__half2 h) { return __builtin_bit_cast(uint, h); }

// ---------------- setup: zero ∪ prepw ∪ bounds (block-range partitioned) ----------------

__global__ __launch_bounds__(256) void k_setup(int* __restrict__ zb,
                                               const float* __restrict__ W1,
                                               const float* __restrict__ W2,
                                               short8v* __restrict__ o1,
                                               short8v* __restrict__ o2,
                                               const int* __restrict__ batch,
                                               int* __restrict__ gstart,
                                               int* __restrict__ gend) {
    int b = blockIdx.x, t = threadIdx.x;
    if (b < 4) {
        int i = b * 256 + t;
        if (i < NZ) zb[i] = 0;
    } else if (b < 6) {
        const float* W = (b == 5) ? W2 : W1;
        short8v* o = (b == 5) ? o2 : o1;
        for (int s = t; s < 2048; s += 256) {
            int p = s >> 6, l = s & 63;
            int kb = (p >> 3) * 32 + ((l >> 4) * 8);
            int j = (p & 7) * 16 + (l & 15);
            short8v v;
            #pragma unroll
            for (int i = 0; i < 8; ++i)
                v[i] = f2h_s(W[(size_t)(kb + i) * 128 + j]);
            o[s] = v;
        }
    } else {
        int i = (b - 6) * 256 + t;
        if (i < NNODES) {
            int bb = batch[i];
            if (i == 0 || batch[i - 1] != bb) gstart[bb] = i;
            if (i == NNODES - 1 || batch[i + 1] != bb) gend[bb] = i + 1;
        }
    }
}

// ---------------- P1: bucket scatter, 4096 edges/block, direct atomic reservation ----------------

#define P1_EPT 16
__global__ __launch_bounds__(256) void k_bscatter(const int* __restrict__ src,
                                                  const int* __restrict__ dst,
                                                  int* __restrict__ bcur,
                                                  uint* __restrict__ pairs, int E) {
    __shared__ int h[NB];
    __shared__ int base[NB];
    int t = threadIdx.x;
    long long c0 = (long long)blockIdx.x * 4096;
    if (c0 >= E) return;
    for (int i = t; i < NB; i += 256) h[i] = 0;
    __syncthreads();
    int myb[P1_EPT], mylp[P1_EPT];
    uint myv[P1_EPT];
    #pragma unroll
    for (int k = 0; k < P1_EPT; ++k) {
        long long e = c0 + t + k * 256;
        if (e < E) {
            int d = dst[e];
            myv[k] = (uint)src[e] | ((uint)(d & (BRANGE - 1)) << 24);
            myb[k] = d >> BSHIFT;
            mylp[k] = atomicAdd(&h[myb[k]], 1);
        } else myb[k] = -1;
    }
    __syncthreads();
    for (int i = t; i < NB; i += 256)
        base[i] = h[i] ? atomicAdd(&bcur[i], h[i]) : 0;
    __syncthreads();
    #pragma unroll
    for (int k = 0; k < P1_EPT; ++k)
        if (myb[k] >= 0) {
            int pos = base[myb[k]] + mylp[k];
            if (pos < CAP)
                pairs[(size_t)myb[k] * CAP + pos] = myv[k];
        }
}

// ---------------- fused per-bucket: histogram -> dinv + node ranges -> CSR scatter ----------------

__global__ __launch_bounds__(256) void k_build(const uint* __restrict__ pairs,
                                               const int* __restrict__ bcur,
                                               int2* __restrict__ nr,
                                               float* __restrict__ dinv,
                                               int* __restrict__ csr, int N) {
    __shared__ int h[256];
    __shared__ int sh[256];
    __shared__ int cur[BRANGE];
    int b = blockIdx.x, t = threadIdx.x;
    h[t] = 0;
    __syncthreads();
    const int p0 = b * CAP;
    const int cntb = min(bcur[b], CAP);
    for (int p = t; p < cntb; p += 256)
        atomicAdd(&h[pairs[p0 + p] >> 24], 1);
    __syncthreads();
    int myh = h[t];
    sh[t] = myh;
    __syncthreads();
    #pragma unroll
    for (int d = 1; d < 256; d <<= 1) {
        int val = (t >= d) ? sh[t - d] : 0;
        __syncthreads();
        sh[t] += val;
        __syncthreads();
    }
    int excl = sh[t] - myh;
    int node = (b << BSHIFT) + t;
    if (t < BRANGE) {
        cur[t] = p0 + excl;
        if (node < N) {
            nr[node] = make_int2(p0 + excl, p0 + excl + myh);
            dinv[node] = rsqrtf((float)(myh + 1));
        }
    }
    __syncthreads();
    for (int p = t; p < cntb; p += 256) {
        uint pr = pairs[p0 + p];
        int pos = atomicAdd(&cur[pr >> 24], 1);
        csr[pos] = (int)(pr & 0x00FFFFFFu);
    }
}

// ---------------- GEMM1 (f32 in): msg1[n,128] = (X @ W1) * dinv[row], fp16 out ----------------

__global__ __launch_bounds__(256) void k_gemm_f32(const float* __restrict__ X,
                                                  const short8v* __restrict__ wf,
                                                  const float* __restrict__ dinv,
                                                  ushort* __restrict__ Y, int nrows) {
    __shared__ short8v sW[2048];
    const int tid = threadIdx.x;
    const int lane = tid & 63;
    const int w = tid >> 6;

    for (int s = tid; s < 2048; s += 256) sW[s] = wf[s];
    __syncthreads();

    const int row0 = blockIdx.x * 64 + w * 16;
    const int arow = row0 + (lane & 15);
    float4v acc[8];
    #pragma unroll
    for (int ct = 0; ct < 8; ++ct) acc[ct] = (float4v)0.f;

    #pragma unroll
    for (int kk = 0; kk < 4; ++kk) {
        short8v a = (short8v)0;
        if (arow < nrows) {
            const float* xp = X + (size_t)arow * 128 + kk * 32 + ((lane >> 4) * 8);
            float4 f0 = ((const float4*)xp)[0];
            float4 f1 = ((const float4*)xp)[1];
            a[0] = f2h_s(f0.x); a[1] = f2h_s(f0.y);
            a[2] = f2h_s(f0.z); a[3] = f2h_s(f0.w);
            a[4] = f2h_s(f1.x); a[5] = f2h_s(f1.y);
            a[6] = f2h_s(f1.z); a[7] = f2h_s(f1.w);
        }
        #pragma unroll
        for (int ct = 0; ct < 8; ++ct)
            acc[ct] = __builtin_amdgcn_mfma_f32_16x16x32_f16(a, sW[(kk * 8 + ct) * 64 + lane],
                                                             acc[ct], 0, 0, 0);
    }

    const int orow = row0 + ((lane >> 4) << 2);
    #pragma unroll
    for (int r = 0; r < 4; ++r) {
        int row = orow + r;
        if (row < nrows) {
            float dr = dinv[row];
            #pragma unroll
            for (int ct = 0; ct < 8; ++ct)
                Y[(size_t)row * 128 + ct * 16 + (lane & 15)] = f2h_u(acc[ct][r] * dr);
        }
    }
}

// ---------------- FUSED agg1 + GEMM2: 16 nodes/block (grid 6250, 25000 waves) ----------------
// Phase 1: each of 4 waves aggregates 4 nodes (agg_pool structure) -> LDS 16xLP tile.
// Phase 2: GEMM split by output columns: wave w computes ct in {2w, 2w+1} (8 MFMAs),
// A rows shared from LDS, W2 fragments from global (L2-hot).

__global__ __launch_bounds__(256, 8) void k_agg_gemm(const uint* __restrict__ msg,
                                                     const float* __restrict__ dinv,
                                                     const int2* __restrict__ nr,
                                                     const int* __restrict__ csr,
                                                     const float* __restrict__ bias,
                                                     const short8v* __restrict__ wf,
                                                     ushort* __restrict__ Y, int n) {
    __shared__ ushort ht[16 * LP];  // 4.35 KB
    const int t = threadIdx.x;
    const int lane = t & 63;
    const int w = t >> 6;
    const int row0 = blockIdx.x * 16;
    const float bx = bias[lane * 2];
    const float by = bias[lane * 2 + 1];

    // phase 1: each wave aggregates 4 nodes
    for (int i = 0; i < 4; ++i) {
        const int r = w * 4 + i;
        const int wid = row0 + r;   // grid exact: 6250*16 == N
        __half2 a0 = u2h2(msg[(size_t)wid * 64 + lane]);
        __half2 a1 = u2h2(0u), a2 = u2h2(0u);
        const int2 rg = nr[wid];
        const int e0 = rg.x, e1 = rg.y;
        for (int e = e0; e < e1; e += 64) {
            int me = e + lane;
            int sidx = (me < e1) ? csr[me] : 0;
            int cnt = min(64, e1 - e);
            for (int kb = 0; kb < cnt; kb += 6) {
                int lim = cnt - 1;
                int s0 = __shfl(sidx, min(kb + 0, lim));
                int s1 = __shfl(sidx, min(kb + 1, lim));
                int s2 = __shfl(sidx, min(kb + 2, lim));
                int s3 = __shfl(sidx, min(kb + 3, lim));
                int s4 = __shfl(sidx, min(kb + 4, lim));
                int s5 = __shfl(sidx, min(kb + 5, lim));
                uint u0 = msg[(size_t)s0 * 64 + lane];
                uint u1 = msg[(size_t)s1 * 64 + lane];
                uint u2 = msg[(size_t)s2 * 64 + lane];
                uint u3 = msg[(size_t)s3 * 64 + lane];
                uint u4 = msg[(size_t)s4 * 64 + lane];
                uint u5 = msg[(size_t)s5 * 64 + lane];
                u1 = (kb + 1 < cnt) ? u1 : 0u;
                u2 = (kb + 2 < cnt) ? u2 : 0u;
                u3 = (kb + 3 < cnt) ? u3 : 0u;
                u4 = (kb + 4 < cnt) ? u4 : 0u;
                u5 = (kb + 5 < cnt) ? u5 : 0u;
                a0 = __hadd2(a0, u2h2(u0));
                a1 = __hadd2(a1, u2h2(u1));
                a2 = __hadd2(a2, u2h2(u2));
                a0 = __hadd2(a0, u2h2(u3));
                a1 = __hadd2(a1, u2h2(u4));
                a2 = __hadd2(a2, u2h2(u5));
            }
        }
        __half2 acc = __hadd2(__hadd2(a0, a1), a2);
        float2 f = __half22float2(acc);
        float dd = dinv[wid];
        float ax = fmaxf(f.x * dd + bx, 0.f);
        float ay = fmaxf(f.y * dd + by, 0.f);
        *(uint*)&ht[r * LP + lane * 2] = h22u(__floats2half2_rn(ax, ay));
    }
    __syncthreads();

    // phase 2: column-split GEMM; wave w does ct = 2w, 2w+1
    float4v acc[2];
    acc[0] = (float4v)0.f;
    acc[1] = (float4v)0.f;
    const int arow = lane & 15;
    const int ct0 = w * 2;
    #pragma unroll
    for (int kk = 0; kk < 4; ++kk) {
        short8v a = *(const short8v*)&ht[arow * LP + kk * 32 + ((lane >> 4) * 8)];
        acc[0] = __builtin_amdgcn_mfma_f32_16x16x32_f16(a, wf[(kk * 8 + ct0) * 64 + lane],
                                                        acc[0], 0, 0, 0);
        acc[1] = __builtin_amdgcn_mfma_f32_16x16x32_f16(a, wf[(kk * 8 + ct0 + 1) * 64 + lane],
                                                        acc[1], 0, 0, 0);
    }
    const int orow = row0 + ((lane >> 4) << 2);
    #pragma unroll
    for (int r = 0; r < 4; ++r) {
        int row = orow + r;
        float dr = dinv[row];
        Y[(size_t)row * 128 + ct0 * 16 + (lane & 15)]       = f2h_u(acc[0][r] * dr);
        Y[(size_t)row * 128 + (ct0 + 1) * 16 + (lane & 15)] = f2h_u(acc[1][r] * dr);
    }
}

// ---------------- FUSED agg2 + pool: per-block (4 nodes) partial sums, A/B by graph ----------------

__global__ __launch_bounds__(256) void k_agg_pool(const uint* __restrict__ msg,
                                                  const float* __restrict__ dinv,
                                                  const int2* __restrict__ nr,
                                                  const int* __restrict__ csr,
                                                  const int* __restrict__ batch,
                                                  float* __restrict__ pA,
                                                  float* __restrict__ pB) {
    __shared__ float red[4][128];
    __shared__ int selw[4];
    const int blk = blockIdx.x;
    const int t = threadIdx.x;
    const int lane = t & 63;
    const int w = t >> 6;
    const int wid = blk * 4 + w;  // N % 4 == 0, always valid

    __half2 a0 = u2h2(msg[(size_t)wid * 64 + lane]);
    __half2 a1 = u2h2(0u), a2 = u2h2(0u);
    const int2 rg = nr[wid];
    const int e0 = rg.x, e1 = rg.y;
    for (int e = e0; e < e1; e += 64) {
        int me = e + lane;
        int sidx = (me < e1) ? csr[me] : 0;
        int cnt = min(64, e1 - e);
        for (int kb = 0; kb < cnt; kb += 6) {
            int lim = cnt - 1;
            int s0 = __shfl(sidx, min(kb + 0, lim));
            int s1 = __shfl(sidx, min(kb + 1, lim));
            int s2 = __shfl(sidx, min(kb + 2, lim));
            int s3 = __shfl(sidx, min(kb + 3, lim));
            int s4 = __shfl(sidx, min(kb + 4, lim));
            int s5 = __shfl(sidx, min(kb + 5, lim));
            uint u0 = msg[(size_t)s0 * 64 + lane];
            uint u1 = msg[(size_t)s1 * 64 + lane];
            uint u2 = msg[(size_t)s2 * 64 + lane];
            uint u3 = msg[(size_t)s3 * 64 + lane];
            uint u4 = msg[(size_t)s4 * 64 + lane];
            uint u5 = msg[(size_t)s5 * 64 + lane];
            u1 = (kb + 1 < cnt) ? u1 : 0u;
            u2 = (kb + 2 < cnt) ? u2 : 0u;
            u3 = (kb + 3 < cnt) ? u3 : 0u;
            u4 = (kb + 4 < cnt) ? u4 : 0u;
            u5 = (kb + 5 < cnt) ? u5 : 0u;
            a0 = __hadd2(a0, u2h2(u0));
            a1 = __hadd2(a1, u2h2(u1));
            a2 = __hadd2(a2, u2h2(u2));
            a0 = __hadd2(a0, u2h2(u3));
            a1 = __hadd2(a1, u2h2(u4));
            a2 = __hadd2(a2, u2h2(u5));
        }
    }
    __half2 acc = __hadd2(__hadd2(a0, a1), a2);
    float2 f = __half22float2(acc);
    float dd = dinv[wid];
    red[w][lane * 2] = f.x * dd;
    red[w][lane * 2 + 1] = f.y * dd;
    if (lane == 0) selw[w] = (batch[wid] != batch[blk * 4]) ? 1 : 0;
    __syncthreads();
    if (t < 128) {
        float a = 0.f, b = 0.f;
        #pragma unroll
        for (int ww = 0; ww < 4; ++ww) {
            float v = red[ww][t];
            if (selw[ww]) b += v; else a += v;
        }
        pA[(size_t)blk * 128 + t] = a;
        if (selw[0] | selw[1] | selw[2] | selw[3])
            pB[(size_t)blk * 128 + t] = b;
    }
}

// ---------------- final: per-graph reduce (512 threads, 4-way strided) + linear head ----------------

__global__ __launch_bounds__(512) void k_final(const float* __restrict__ pA,
                                               const float* __restrict__ pB,
                                               const int* __restrict__ batch,
                                               const int* __restrict__ gstart,
                                               const int* __restrict__ gend,
                                               const float* __restrict__ b2,
                                               const float* __restrict__ linW,
                                               const float* __restrict__ linb,
                                               float* __restrict__ out) {
    __shared__ float sq[4][128];
    __shared__ float red[128][8];
    int g = blockIdx.x;
    int t = threadIdx.x;
    int c = t & 127;   // channel
    int q = t >> 7;    // quarter 0..3
    int b0 = gstart[g] >> 2;
    int b1 = (gend[g] - 1) >> 2;
    float v = 0.f;
    #pragma unroll 4
    for (int b = b0 + 1 + q; b <= b1; b += 4)
        v += pA[(size_t)b * 128 + c];
    if (q == 0)
        v += ((batch[b0 * 4] != g) ? pB : pA)[(size_t)b0 * 128 + c];
    sq[q][c] = v;
    __syncthreads();
    if (t < 128) {
        float sv = sq[0][t] + sq[1][t] + sq[2][t] + sq[3][t];
        float cnt = (float)(gend[g] - gstart[g]);
        sv = sv / fmaxf(cnt, 1.0f) + b2[t];
        #pragma unroll
        for (int k = 0; k < 8; ++k) red[t][k] = sv * linW[(size_t)t * 8 + k];
    }
    __syncthreads();
    #pragma unroll
    for (int st = 64; st > 0; st >>= 1) {
        if (t < st) {
            #pragma unroll
            for (int k = 0; k < 8; ++k) red[t][k] += red[t + st][k];
        }
        __syncthreads();
    }
    if (t < 8) out[(size_t)g * 8 + t] = red[0][t] + linb[t];
}

// ---------------- launch ----------------

extern "C" void kernel_launch(void* const* d_in, const int* in_sizes, int n_in,
                              void* d_out, int out_size, void* d_ws, size_t ws_size,
                              hipStream_t stream) {
    const float* x     = (const float*)d_in[0];
    const int*   ei    = (const int*)d_in[1];  // [2,E]: src = ei, dst = ei+E
    const int*   batch = (const int*)d_in[2];
    const float* W1    = (const float*)d_in[3];
    const float* b1    = (const float*)d_in[4];
    const float* W2    = (const float*)d_in[5];
    const float* b2    = (const float*)d_in[6];
    const float* linW  = (const float*)d_in[7];
    const float* linb  = (const float*)d_in[8];
    float* out = (float*)d_out;

    const int N = NNODES, E = NEDGES;
    const int* src = ei;
    const int* dst = ei + E;

    char* ws = (char*)d_ws;
    uint*  bufA16 = (uint*)ws;     ws += (size_t)N * 64 * 4;   // msg1 (fp16), 25.6MB
    uint*  bufH16 = (uint*)ws;     ws += (size_t)N * 64 * 4;   // msg2 (fp16), 25.6MB
    float* dinv   = (float*)ws;    ws += (size_t)N * 4;
    int2*  nr     = (int2*)ws;     ws += (size_t)N * 8;        // per-node (start,end)
    int*   csr    = (int*)ws;      ws += (size_t)NB * CAP * 4; // 12.8MB bucket frames
    int*   bcur   = (int*)ws;      ws += NB * 4;               // zero region
    int*   gstart = (int*)ws;      ws += NGRAPHS * 4;
    int*   gend   = (int*)ws;      ws += NGRAPHS * 4;
    short8v* wf1  = (short8v*)ws;  ws += 2048 * 16;            // fragment-ordered W1 (32KB)
    short8v* wf2  = (short8v*)ws;  ws += 2048 * 16;            // fragment-ordered W2 (32KB)
    float* pA     = (float*)ws;    ws += (size_t)NAB * 128 * 4;  // 12.8MB
    float* pB     = (float*)ws;    ws += (size_t)NAB * 128 * 4;  // 12.8MB
    // pairs aliases bufH16 (12.8MB < 25.6MB): CSR build completes before msg2 written
    uint*  pairs  = (uint*)bufH16;

    const int B = 256;

    // setup: zero(4) + prepw(2) + bounds(391) = 397 blocks
    k_setup<<<397, B, 0, stream>>>(bcur, W1, W2, wf1, wf2, batch, gstart, gend);

    // CSR build
    k_bscatter<<<(E + 4095) / 4096, B, 0, stream>>>(src, dst, bcur, pairs, E);
    k_build<<<NB, B, 0, stream>>>(pairs, bcur, nr, dinv, csr, N);

    // layer 1 GEMM: msg1 = (x @ W1) * dinv
    k_gemm_f32<<<(N + 63) / 64, B, 0, stream>>>(x, wf1, dinv, (ushort*)bufA16, N);

    // fused agg1 + GEMM2: msg2 = (relu(agg(msg1)+b1) @ W2) * dinv  (16 nodes/block)
    k_agg_gemm<<<N / 16, B, 0, stream>>>(bufA16, dinv, nr, csr, b1, wf2,
                                         (ushort*)bufH16, N);

    // fused agg2 + pool: per-block partial sums of h2
    k_agg_pool<<<NAB, B, 0, stream>>>(bufH16, dinv, nr, csr, batch, pA, pB);

    // per-graph reduce + head
    k_final<<<NGRAPHS, 512, 0, stream>>>(pA, pB, batch, gstart, gend, b2, linW, linb, out);
}

// Round 21
// 200.415 us; speedup vs baseline: 1.6817x; 1.0203x over previous
//
#include <hip/hip_runtime.h>
#include <hip/hip_fp16.h>
#include <cstdint>
#include <cstddef>

#define NNODES 100000
#define NEDGES 1600000
#define NGRAPHS 64
#define BSHIFT 7
#define BRANGE 128
#define NB 782   // ceil(NNODES / 128)
#define CAP 4096 // edges per bucket frame (mean 2046, sd 45 -> >40 sigma headroom)
#define NZ NB    // ints to zero (bcur)
#define LP 136   // LDS row pitch in shorts (272B: 16B-aligned)
#define NAB 25000 // agg2/pool blocks (N/4)

typedef short short8v __attribute__((ext_vector_type(8)));
typedef float float4v __attribute__((ext_vector_type(4)));

__device__ inline short f2h_s(float f) {
    __half h = __float2half(f);
    return __builtin_bit_cast(short, h);
}
__device__ inline ushort f2h_u(float f) {
    __half h = __float2half(f);
    return __builtin_bit_cast(ushort, h);
}
__device__ inline __half2 u2h2(uint u) { return __builtin_bit_cast(__half2, u); }
__device__ inline uint h22u(__half2 h) { return __builtin_bit_cast(uint, h); }

// ---------------- setup: zero ∪ prepw ∪ bounds (block-range partitioned) ----------------

__global__ __launch_bounds__(256) void k_setup(int* __restrict__ zb,
                                               const float* __restrict__ W1,
                                               const float* __restrict__ W2,
                                               short8v* __restrict__ o1,
                                               short8v* __restrict__ o2,
                                               const int* __restrict__ batch,
                                               int* __restrict__ gstart,
                                               int* __restrict__ gend) {
    int b = blockIdx.x, t = threadIdx.x;
    if (b < 4) {
        int i = b * 256 + t;
        if (i < NZ) zb[i] = 0;
    } else if (b < 6) {
        const float* W = (b == 5) ? W2 : W1;
        short8v* o = (b == 5) ? o2 : o1;
        for (int s = t; s < 2048; s += 256) {
            int p = s >> 6, l = s & 63;
            int kb = (p >> 3) * 32 + ((l >> 4) * 8);
            int j = (p & 7) * 16 + (l & 15);
            short8v v;
            #pragma unroll
            for (int i = 0; i < 8; ++i)
                v[i] = f2h_s(W[(size_t)(kb + i) * 128 + j]);
            o[s] = v;
        }
    } else {
        int i = (b - 6) * 256 + t;
        if (i < NNODES) {
            int bb = batch[i];
            if (i == 0 || batch[i - 1] != bb) gstart[bb] = i;
            if (i == NNODES - 1 || batch[i + 1] != bb) gend[bb] = i + 1;
        }
    }
}

// ---------------- P1: bucket scatter, 4096 edges/block, direct atomic reservation ----------------

#define P1_EPT 16
__global__ __launch_bounds__(256) void k_bscatter(const int* __restrict__ src,
                                                  const int* __restrict__ dst,
                                                  int* __restrict__ bcur,
                                                  uint* __restrict__ pairs, int E) {
    __shared__ int h[NB];
    __shared__ int base[NB];
    int t = threadIdx.x;
    long long c0 = (long long)blockIdx.x * 4096;
    if (c0 >= E) return;
    for (int i = t; i < NB; i += 256) h[i] = 0;
    __syncthreads();
    int myb[P1_EPT], mylp[P1_EPT];
    uint myv[P1_EPT];
    #pragma unroll
    for (int k = 0; k < P1_EPT; ++k) {
        long long e = c0 + t + k * 256;
        if (e < E) {
            int d = dst[e];
            myv[k] = (uint)src[e] | ((uint)(d & (BRANGE - 1)) << 24);
            myb[k] = d >> BSHIFT;
            mylp[k] = atomicAdd(&h[myb[k]], 1);
        } else myb[k] = -1;
    }
    __syncthreads();
    for (int i = t; i < NB; i += 256)
        base[i] = h[i] ? atomicAdd(&bcur[i], h[i]) : 0;
    __syncthreads();
    #pragma unroll
    for (int k = 0; k < P1_EPT; ++k)
        if (myb[k] >= 0) {
            int pos = base[myb[k]] + mylp[k];
            if (pos < CAP)
                pairs[(size_t)myb[k] * CAP + pos] = myv[k];
        }
}

// ---------------- fused per-bucket: histogram -> dinv + node ranges -> CSR scatter ----------------

__global__ __launch_bounds__(256) void k_build(const uint* __restrict__ pairs,
                                               const int* __restrict__ bcur,
                                               int2* __restrict__ nr,
                                               float* __restrict__ dinv,
                                               int* __restrict__ csr, int N) {
    __shared__ int h[256];
    __shared__ int sh[256];
    __shared__ int cur[BRANGE];
    int b = blockIdx.x, t = threadIdx.x;
    h[t] = 0;
    __syncthreads();
    const int p0 = b * CAP;
    const int cntb = min(bcur[b], CAP);
    for (int p = t; p < cntb; p += 256)
        atomicAdd(&h[pairs[p0 + p] >> 24], 1);
    __syncthreads();
    int myh = h[t];
    sh[t] = myh;
    __syncthreads();
    #pragma unroll
    for (int d = 1; d < 256; d <<= 1) {
        int val = (t >= d) ? sh[t - d] : 0;
        __syncthreads();
        sh[t] += val;
        __syncthreads();
    }
    int excl = sh[t] - myh;
    int node = (b << BSHIFT) + t;
    if (t < BRANGE) {
        cur[t] = p0 + excl;
        if (node < N) {
            nr[node] = make_int2(p0 + excl, p0 + excl + myh);
            dinv[node] = rsqrtf((float)(myh + 1));
        }
    }
    __syncthreads();
    for (int p = t; p < cntb; p += 256) {
        uint pr = pairs[p0 + p];
        int pos = atomicAdd(&cur[pr >> 24], 1);
        csr[pos] = (int)(pr & 0x00FFFFFFu);
    }
}

// ---------------- GEMM1: 16 rows/block, coalesced LDS staging, column-split MFMA ----------------
// msg1[n,128] = (X_f32 @ W1) * dinv[row], fp16 out. W1 fragments from global (L2-hot).

__global__ __launch_bounds__(256) void k_gemm_f32(const float4* __restrict__ X4,
                                                  const short8v* __restrict__ wf,
                                                  const float* __restrict__ dinv,
                                                  ushort* __restrict__ Y, int n) {
    __shared__ ushort ht[16 * LP];  // 4.35 KB
    const int t = threadIdx.x;
    const int lane = t & 63;
    const int w = t >> 6;
    const int row0 = blockIdx.x * 16;

    // stage: coalesced float4 reads of the 16x128 x-tile, convert to fp16 in LDS
    #pragma unroll
    for (int s = t; s < 16 * 32; s += 256) {
        int row = s >> 5, q = s & 31;
        float4 v = X4[(size_t)(row0 + row) * 32 + q];
        ushort2 h0 = make_ushort2(f2h_u(v.x), f2h_u(v.y));
        ushort2 h1 = make_ushort2(f2h_u(v.z), f2h_u(v.w));
        *(ushort2*)&ht[row * LP + q * 4] = h0;
        *(ushort2*)&ht[row * LP + q * 4 + 2] = h1;
    }
    __syncthreads();

    // column-split GEMM: wave w does ct = 2w, 2w+1
    float4v acc[2];
    acc[0] = (float4v)0.f;
    acc[1] = (float4v)0.f;
    const int arow = lane & 15;
    const int ct0 = w * 2;
    #pragma unroll
    for (int kk = 0; kk < 4; ++kk) {
        short8v a = *(const short8v*)&ht[arow * LP + kk * 32 + ((lane >> 4) * 8)];
        acc[0] = __builtin_amdgcn_mfma_f32_16x16x32_f16(a, wf[(kk * 8 + ct0) * 64 + lane],
                                                        acc[0], 0, 0, 0);
        acc[1] = __builtin_amdgcn_mfma_f32_16x16x32_f16(a, wf[(kk * 8 + ct0 + 1) * 64 + lane],
                                                        acc[1], 0, 0, 0);
    }
    const int orow = row0 + ((lane >> 4) << 2);
    #pragma unroll
    for (int r = 0; r < 4; ++r) {
        int row = orow + r;
        float dr = dinv[row];
        Y[(size_t)row * 128 + ct0 * 16 + (lane & 15)]       = f2h_u(acc[0][r] * dr);
        Y[(size_t)row * 128 + (ct0 + 1) * 16 + (lane & 15)] = f2h_u(acc[1][r] * dr);
    }
}

// ---------------- FUSED agg1 + GEMM2: 8 waves, 2 nodes/wave, 1 col-tile/wave ----------------

__global__ __launch_bounds__(512) void k_agg_gemm(const uint* __restrict__ msg,
                                                  const float* __restrict__ dinv,
                                                  const int2* __restrict__ nr,
                                                  const int* __restrict__ csr,
                                                  const float* __restrict__ bias,
                                                  const short8v* __restrict__ wf,
                                                  ushort* __restrict__ Y, int n) {
    __shared__ ushort ht[16 * LP];  // 4.35 KB
    const int t = threadIdx.x;
    const int lane = t & 63;
    const int w = t >> 6;           // 0..7
    const int row0 = blockIdx.x * 16;
    const float bx = bias[lane * 2];
    const float by = bias[lane * 2 + 1];

    // phase 1: each wave aggregates 2 nodes
    #pragma unroll
    for (int i = 0; i < 2; ++i) {
        const int r = w * 2 + i;
        const int wid = row0 + r;   // grid exact: 6250*16 == N
        __half2 a0 = u2h2(msg[(size_t)wid * 64 + lane]);
        __half2 a1 = u2h2(0u), a2 = u2h2(0u);
        const int2 rg = nr[wid];
        const int e0 = rg.x, e1 = rg.y;
        for (int e = e0; e < e1; e += 64) {
            int me = e + lane;
            int sidx = (me < e1) ? csr[me] : 0;
            int cnt = min(64, e1 - e);
            for (int kb = 0; kb < cnt; kb += 6) {
                int lim = cnt - 1;
                int s0 = __shfl(sidx, min(kb + 0, lim));
                int s1 = __shfl(sidx, min(kb + 1, lim));
                int s2 = __shfl(sidx, min(kb + 2, lim));
                int s3 = __shfl(sidx, min(kb + 3, lim));
                int s4 = __shfl(sidx, min(kb + 4, lim));
                int s5 = __shfl(sidx, min(kb + 5, lim));
                uint u0 = msg[(size_t)s0 * 64 + lane];
                uint u1 = msg[(size_t)s1 * 64 + lane];
                uint u2 = msg[(size_t)s2 * 64 + lane];
                uint u3 = msg[(size_t)s3 * 64 + lane];
                uint u4 = msg[(size_t)s4 * 64 + lane];
                uint u5 = msg[(size_t)s5 * 64 + lane];
                u1 = (kb + 1 < cnt) ? u1 : 0u;
                u2 = (kb + 2 < cnt) ? u2 : 0u;
                u3 = (kb + 3 < cnt) ? u3 : 0u;
                u4 = (kb + 4 < cnt) ? u4 : 0u;
                u5 = (kb + 5 < cnt) ? u5 : 0u;
                a0 = __hadd2(a0, u2h2(u0));
                a1 = __hadd2(a1, u2h2(u1));
                a2 = __hadd2(a2, u2h2(u2));
                a0 = __hadd2(a0, u2h2(u3));
                a1 = __hadd2(a1, u2h2(u4));
                a2 = __hadd2(a2, u2h2(u5));
            }
        }
        __half2 acc = __hadd2(__hadd2(a0, a1), a2);
        float2 f = __half22float2(acc);
        float dd = dinv[wid];
        float ax = fmaxf(f.x * dd + bx, 0.f);
        float ay = fmaxf(f.y * dd + by, 0.f);
        *(uint*)&ht[r * LP + lane * 2] = h22u(__floats2half2_rn(ax, ay));
    }
    __syncthreads();

    // phase 2: wave w computes column-tile ct = w (4 MFMAs)
    float4v acc = (float4v)0.f;
    const int arow = lane & 15;
    #pragma unroll
    for (int kk = 0; kk < 4; ++kk) {
        short8v a = *(const short8v*)&ht[arow * LP + kk * 32 + ((lane >> 4) * 8)];
        acc = __builtin_amdgcn_mfma_f32_16x16x32_f16(a, wf[(kk * 8 + w) * 64 + lane],
                                                     acc, 0, 0, 0);
    }
    const int orow = row0 + ((lane >> 4) << 2);
    #pragma unroll
    for (int r = 0; r < 4; ++r) {
        int row = orow + r;
        float dr = dinv[row];
        Y[(size_t)row * 128 + w * 16 + (lane & 15)] = f2h_u(acc[r] * dr);
    }
}

// ---------------- FUSED agg2 + pool: per-block (4 nodes) partial sums, A/B by graph ----------------

__global__ __launch_bounds__(256) void k_agg_pool(const uint* __restrict__ msg,
                                                  const float* __restrict__ dinv,
                                                  const int2* __restrict__ nr,
                                                  const int* __restrict__ csr,
                                                  const int* __restrict__ batch,
                                                  float* __restrict__ pA,
                                                  float* __restrict__ pB) {
    __shared__ float red[4][128];
    __shared__ int selw[4];
    const int blk = blockIdx.x;
    const int t = threadIdx.x;
    const int lane = t & 63;
    const int w = t >> 6;
    const int wid = blk * 4 + w;  // N % 4 == 0, always valid

    __half2 a0 = u2h2(msg[(size_t)wid * 64 + lane]);
    __half2 a1 = u2h2(0u), a2 = u2h2(0u);
    const int2 rg = nr[wid];
    const int e0 = rg.x, e1 = rg.y;
    for (int e = e0; e < e1; e += 64) {
        int me = e + lane;
        int sidx = (me < e1) ? csr[me] : 0;
        int cnt = min(64, e1 - e);
        for (int kb = 0; kb < cnt; kb += 6) {
            int lim = cnt - 1;
            int s0 = __shfl(sidx, min(kb + 0, lim));
            int s1 = __shfl(sidx, min(kb + 1, lim));
            int s2 = __shfl(sidx, min(kb + 2, lim));
            int s3 = __shfl(sidx, min(kb + 3, lim));
            int s4 = __shfl(sidx, min(kb + 4, lim));
            int s5 = __shfl(sidx, min(kb + 5, lim));
            uint u0 = msg[(size_t)s0 * 64 + lane];
            uint u1 = msg[(size_t)s1 * 64 + lane];
            uint u2 = msg[(size_t)s2 * 64 + lane];
            uint u3 = msg[(size_t)s3 * 64 + lane];
            uint u4 = msg[(size_t)s4 * 64 + lane];
            uint u5 = msg[(size_t)s5 * 64 + lane];
            u1 = (kb + 1 < cnt) ? u1 : 0u;
            u2 = (kb + 2 < cnt) ? u2 : 0u;
            u3 = (kb + 3 < cnt) ? u3 : 0u;
            u4 = (kb + 4 < cnt) ? u4 : 0u;
            u5 = (kb + 5 < cnt) ? u5 : 0u;
            a0 = __hadd2(a0, u2h2(u0));
            a1 = __hadd2(a1, u2h2(u1));
            a2 = __hadd2(a2, u2h2(u2));
            a0 = __hadd2(a0, u2h2(u3));
            a1 = __hadd2(a1, u2h2(u4));
            a2 = __hadd2(a2, u2h2(u5));
        }
    }
    __half2 acc = __hadd2(__hadd2(a0, a1), a2);
    float2 f = __half22float2(acc);
    float dd = dinv[wid];
    red[w][lane * 2] = f.x * dd;
    red[w][lane * 2 + 1] = f.y * dd;
    if (lane == 0) selw[w] = (batch[wid] != batch[blk * 4]) ? 1 : 0;
    __syncthreads();
    if (t < 128) {
        float a = 0.f, b = 0.f;
        #pragma unroll
        for (int ww = 0; ww < 4; ++ww) {
            float v = red[ww][t];
            if (selw[ww]) b += v; else a += v;
        }
        pA[(size_t)blk * 128 + t] = a;
        if (selw[0] | selw[1] | selw[2] | selw[3])
            pB[(size_t)blk * 128 + t] = b;
    }
}

// ---------------- final: per-graph reduce (512 threads, 4-way strided) + linear head ----------------

__global__ __launch_bounds__(512) void k_final(const float* __restrict__ pA,
                                               const float* __restrict__ pB,
                                               const int* __restrict__ batch,
                                               const int* __restrict__ gstart,
                                               const int* __restrict__ gend,
                                               const float* __restrict__ b2,
                                               const float* __restrict__ linW,
                                               const float* __restrict__ linb,
                                               float* __restrict__ out) {
    __shared__ float sq[4][128];
    __shared__ float red[128][8];
    int g = blockIdx.x;
    int t = threadIdx.x;
    int c = t & 127;   // channel
    int q = t >> 7;    // quarter 0..3
    int b0 = gstart[g] >> 2;
    int b1 = (gend[g] - 1) >> 2;
    float v = 0.f;
    #pragma unroll 4
    for (int b = b0 + 1 + q; b <= b1; b += 4)
        v += pA[(size_t)b * 128 + c];
    if (q == 0)
        v += ((batch[b0 * 4] != g) ? pB : pA)[(size_t)b0 * 128 + c];
    sq[q][c] = v;
    __syncthreads();
    if (t < 128) {
        float sv = sq[0][t] + sq[1][t] + sq[2][t] + sq[3][t];
        float cnt = (float)(gend[g] - gstart[g]);
        sv = sv / fmaxf(cnt, 1.0f) + b2[t];
        #pragma unroll
        for (int k = 0; k < 8; ++k) red[t][k] = sv * linW[(size_t)t * 8 + k];
    }
    __syncthreads();
    #pragma unroll
    for (int st = 64; st > 0; st >>= 1) {
        if (t < st) {
            #pragma unroll
            for (int k = 0; k < 8; ++k) red[t][k] += red[t + st][k];
        }
        __syncthreads();
    }
    if (t < 8) out[(size_t)g * 8 + t] = red[0][t] + linb[t];
}

// ---------------- launch ----------------

extern "C" void kernel_launch(void* const* d_in, const int* in_sizes, int n_in,
                              void* d_out, int out_size, void* d_ws, size_t ws_size,
                              hipStream_t stream) {
    const float* x     = (const float*)d_in[0];
    const int*   ei    = (const int*)d_in[1];  // [2,E]: src = ei, dst = ei+E
    const int*   batch = (const int*)d_in[2];
    const float* W1    = (const float*)d_in[3];
    const float* b1    = (const float*)d_in[4];
    const float* W2    = (const float*)d_in[5];
    const float* b2    = (const float*)d_in[6];
    const float* linW  = (const float*)d_in[7];
    const float* linb  = (const float*)d_in[8];
    float* out = (float*)d_out;

    const int N = NNODES, E = NEDGES;
    const int* src = ei;
    const int* dst = ei + E;

    char* ws = (char*)d_ws;
    uint*  bufA16 = (uint*)ws;     ws += (size_t)N * 64 * 4;   // msg1 (fp16), 25.6MB
    uint*  bufH16 = (uint*)ws;     ws += (size_t)N * 64 * 4;   // msg2 (fp16), 25.6MB
    float* dinv   = (float*)ws;    ws += (size_t)N * 4;
    int2*  nr     = (int2*)ws;     ws += (size_t)N * 8;        // per-node (start,end)
    int*   csr    = (int*)ws;      ws += (size_t)NB * CAP * 4; // 12.8MB bucket frames
    int*   bcur   = (int*)ws;      ws += NB * 4;               // zero region
    int*   gstart = (int*)ws;      ws += NGRAPHS * 4;
    int*   gend   = (int*)ws;      ws += NGRAPHS * 4;
    short8v* wf1  = (short8v*)ws;  ws += 2048 * 16;            // fragment-ordered W1 (32KB)
    short8v* wf2  = (short8v*)ws;  ws += 2048 * 16;            // fragment-ordered W2 (32KB)
    float* pA     = (float*)ws;    ws += (size_t)NAB * 128 * 4;  // 12.8MB
    float* pB     = (float*)ws;    ws += (size_t)NAB * 128 * 4;  // 12.8MB
    // pairs aliases bufH16 (12.8MB < 25.6MB): CSR build completes before msg2 written
    uint*  pairs  = (uint*)bufH16;

    const int B = 256;

    // setup: zero(4) + prepw(2) + bounds(391) = 397 blocks
    k_setup<<<397, B, 0, stream>>>(bcur, W1, W2, wf1, wf2, batch, gstart, gend);

    // CSR build
    k_bscatter<<<(E + 4095) / 4096, B, 0, stream>>>(src, dst, bcur, pairs, E);
    k_build<<<NB, B, 0, stream>>>(pairs, bcur, nr, dinv, csr, N);

    // layer 1 GEMM: msg1 = (x @ W1) * dinv  (16 rows/block, LDS-staged)
    k_gemm_f32<<<N / 16, B, 0, stream>>>((const float4*)x, wf1, dinv, (ushort*)bufA16, N);

    // fused agg1 + GEMM2: msg2 = (relu(agg(msg1)+b1) @ W2) * dinv  (8 waves, 2 nodes/wave)
    k_agg_gemm<<<N / 16, 512, 0, stream>>>(bufA16, dinv, nr, csr, b1, wf2,
                                           (ushort*)bufH16, N);

    // fused agg2 + pool: per-block partial sums of h2
    k_agg_pool<<<NAB, B, 0, stream>>>(bufH16, dinv, nr, csr, batch, pA, pB);

    // per-graph reduce + head
    k_final<<<NGRAPHS, 512, 0, stream>>>(pA, pB, batch, gstart, gend, b2, linW, linb, out);
}

// Round 22
// 194.721 us; speedup vs baseline: 1.7309x; 1.0292x over previous
//
#include <hip/hip_runtime.h>
#include <hip/hip_fp16.h>
#include <cstdint>
#include <cstddef>

#define NNODES 100000
#define NEDGES 1600000
#define NGRAPHS 64
#define BSHIFT 7
#define BRANGE 128
#define NB 782   // ceil(NNODES / 128)
#define CAP 4096 // edges per bucket frame (mean 2046, sd 45 -> >40 sigma headroom)
#define NZ NB    // ints to zero (bcur)
#define LP 136   // LDS row pitch in shorts (272B: 16B-aligned)
#define NAB 25000 // agg2/pool blocks (N/4)

typedef short short8v __attribute__((ext_vector_type(8)));
typedef float float4v __attribute__((ext_vector_type(4)));

__device__ inline short f2h_s(float f) {
    __half h = __float2half(f);
    return __builtin_bit_cast(short, h);
}
__device__ inline ushort f2h_u(float f) {
    __half h = __float2half(f);
    return __builtin_bit_cast(ushort, h);
}
__device__ inline __half2 u2h2(uint u) { return __builtin_bit_cast(__half2, u); }
__device__ inline uint h22u(__half2 h) { return __builtin_bit_cast(uint, h); }

// ---------------- setup: zero ∪ prepw ∪ bounds (block-range partitioned) ----------------

__global__ __launch_bounds__(256) void k_setup(int* __restrict__ zb,
                                               const float* __restrict__ W1,
                                               const float* __restrict__ W2,
                                               short8v* __restrict__ o1,
                                               short8v* __restrict__ o2,
                                               const int* __restrict__ batch,
                                               int* __restrict__ gstart,
                                               int* __restrict__ gend) {
    int b = blockIdx.x, t = threadIdx.x;
    if (b < 4) {
        int i = b * 256 + t;
        if (i < NZ) zb[i] = 0;
    } else if (b < 6) {
        const float* W = (b == 5) ? W2 : W1;
        short8v* o = (b == 5) ? o2 : o1;
        for (int s = t; s < 2048; s += 256) {
            int p = s >> 6, l = s & 63;
            int kb = (p >> 3) * 32 + ((l >> 4) * 8);
            int j = (p & 7) * 16 + (l & 15);
            short8v v;
            #pragma unroll
            for (int i = 0; i < 8; ++i)
                v[i] = f2h_s(W[(size_t)(kb + i) * 128 + j]);
            o[s] = v;
        }
    } else {
        int i = (b - 6) * 256 + t;
        if (i < NNODES) {
            int bb = batch[i];
            if (i == 0 || batch[i - 1] != bb) gstart[bb] = i;
            if (i == NNODES - 1 || batch[i + 1] != bb) gend[bb] = i + 1;
        }
    }
}

// ---------------- P1: bucket scatter, 512 thr x 8192 edges/block, direct reservation ----------------

#define P1_EPT 16
__global__ __launch_bounds__(512) void k_bscatter(const int* __restrict__ src,
                                                  const int* __restrict__ dst,
                                                  int* __restrict__ bcur,
                                                  uint* __restrict__ pairs, int E) {
    __shared__ int h[NB];
    __shared__ int base[NB];
    int t = threadIdx.x;
    long long c0 = (long long)blockIdx.x * 8192;
    if (c0 >= E) return;
    for (int i = t; i < NB; i += 512) h[i] = 0;
    __syncthreads();
    int myb[P1_EPT], mylp[P1_EPT];
    uint myv[P1_EPT];
    #pragma unroll
    for (int k = 0; k < P1_EPT; ++k) {
        long long e = c0 + t + k * 512;
        if (e < E) {
            int d = dst[e];
            myv[k] = (uint)src[e] | ((uint)(d & (BRANGE - 1)) << 24);
            myb[k] = d >> BSHIFT;
            mylp[k] = atomicAdd(&h[myb[k]], 1);
        } else myb[k] = -1;
    }
    __syncthreads();
    for (int i = t; i < NB; i += 512)
        base[i] = h[i] ? atomicAdd(&bcur[i], h[i]) : 0;
    __syncthreads();
    #pragma unroll
    for (int k = 0; k < P1_EPT; ++k)
        if (myb[k] >= 0) {
            int pos = base[myb[k]] + mylp[k];
            if (pos < CAP)
                pairs[(size_t)myb[k] * CAP + pos] = myv[k];
        }
}

// ---------------- fused per-bucket (512 thr): histogram -> dinv + ranges -> CSR scatter ----------------

__global__ __launch_bounds__(512) void k_build(const uint* __restrict__ pairs,
                                               const int* __restrict__ bcur,
                                               int2* __restrict__ nr,
                                               float* __restrict__ dinv,
                                               int* __restrict__ csr, int N) {
    __shared__ int h[256];
    __shared__ int sh[256];
    __shared__ int cur[BRANGE];
    int b = blockIdx.x, t = threadIdx.x;
    if (t < 256) h[t] = 0;
    __syncthreads();
    const int p0 = b * CAP;
    const int cntb = min(bcur[b], CAP);
    for (int p = t; p < cntb; p += 512)
        atomicAdd(&h[pairs[p0 + p] >> 24], 1);
    __syncthreads();
    int myh = (t < 256) ? h[t] : 0;
    if (t < 256) sh[t] = myh;
    __syncthreads();
    #pragma unroll
    for (int d = 1; d < 256; d <<= 1) {
        int val = (t >= d && t < 256) ? sh[t - d] : 0;
        __syncthreads();
        if (t < 256) sh[t] += val;
        __syncthreads();
    }
    int node = (b << BSHIFT) + t;
    if (t < BRANGE) {
        int excl = sh[t] - myh;
        cur[t] = p0 + excl;
        if (node < N) {
            nr[node] = make_int2(p0 + excl, p0 + excl + myh);
            dinv[node] = rsqrtf((float)(myh + 1));
        }
    }
    __syncthreads();
    for (int p = t; p < cntb; p += 512) {
        uint pr = pairs[p0 + p];
        int pos = atomicAdd(&cur[pr >> 24], 1);
        csr[pos] = (int)(pr & 0x00FFFFFFu);
    }
}

// ---------------- GEMM1: 16 rows/block, coalesced LDS staging, column-split MFMA ----------------

__global__ __launch_bounds__(256) void k_gemm_f32(const float4* __restrict__ X4,
                                                  const short8v* __restrict__ wf,
                                                  const float* __restrict__ dinv,
                                                  ushort* __restrict__ Y, int n) {
    __shared__ ushort ht[16 * LP];  // 4.35 KB
    const int t = threadIdx.x;
    const int lane = t & 63;
    const int w = t >> 6;
    const int row0 = blockIdx.x * 16;

    #pragma unroll
    for (int s = t; s < 16 * 32; s += 256) {
        int row = s >> 5, q = s & 31;
        float4 v = X4[(size_t)(row0 + row) * 32 + q];
        ushort2 h0 = make_ushort2(f2h_u(v.x), f2h_u(v.y));
        ushort2 h1 = make_ushort2(f2h_u(v.z), f2h_u(v.w));
        *(ushort2*)&ht[row * LP + q * 4] = h0;
        *(ushort2*)&ht[row * LP + q * 4 + 2] = h1;
    }
    __syncthreads();

    float4v acc[2];
    acc[0] = (float4v)0.f;
    acc[1] = (float4v)0.f;
    const int arow = lane & 15;
    const int ct0 = w * 2;
    #pragma unroll
    for (int kk = 0; kk < 4; ++kk) {
        short8v a = *(const short8v*)&ht[arow * LP + kk * 32 + ((lane >> 4) * 8)];
        acc[0] = __builtin_amdgcn_mfma_f32_16x16x32_f16(a, wf[(kk * 8 + ct0) * 64 + lane],
                                                        acc[0], 0, 0, 0);
        acc[1] = __builtin_amdgcn_mfma_f32_16x16x32_f16(a, wf[(kk * 8 + ct0 + 1) * 64 + lane],
                                                        acc[1], 0, 0, 0);
    }
    const int orow = row0 + ((lane >> 4) << 2);
    #pragma unroll
    for (int r = 0; r < 4; ++r) {
        int row = orow + r;
        float dr = dinv[row];
        Y[(size_t)row * 128 + ct0 * 16 + (lane & 15)]       = f2h_u(acc[0][r] * dr);
        Y[(size_t)row * 128 + (ct0 + 1) * 16 + (lane & 15)] = f2h_u(acc[1][r] * dr);
    }
}

// ---------------- FUSED agg1 + GEMM2: 8 waves, 2 nodes/wave, 1 col-tile/wave ----------------

__global__ __launch_bounds__(512) void k_agg_gemm(const uint* __restrict__ msg,
                                                  const float* __restrict__ dinv,
                                                  const int2* __restrict__ nr,
                                                  const int* __restrict__ csr,
                                                  const float* __restrict__ bias,
                                                  const short8v* __restrict__ wf,
                                                  ushort* __restrict__ Y, int n) {
    __shared__ ushort ht[16 * LP];  // 4.35 KB
    const int t = threadIdx.x;
    const int lane = t & 63;
    const int w = t >> 6;           // 0..7
    const int row0 = blockIdx.x * 16;
    const float bx = bias[lane * 2];
    const float by = bias[lane * 2 + 1];

    #pragma unroll
    for (int i = 0; i < 2; ++i) {
        const int r = w * 2 + i;
        const int wid = row0 + r;   // grid exact: 6250*16 == N
        __half2 a0 = u2h2(msg[(size_t)wid * 64 + lane]);
        __half2 a1 = u2h2(0u), a2 = u2h2(0u);
        const int2 rg = nr[wid];
        const int e0 = rg.x, e1 = rg.y;
        for (int e = e0; e < e1; e += 64) {
            int me = e + lane;
            int sidx = (me < e1) ? csr[me] : 0;
            int cnt = min(64, e1 - e);
            for (int kb = 0; kb < cnt; kb += 6) {
                int lim = cnt - 1;
                int s0 = __shfl(sidx, min(kb + 0, lim));
                int s1 = __shfl(sidx, min(kb + 1, lim));
                int s2 = __shfl(sidx, min(kb + 2, lim));
                int s3 = __shfl(sidx, min(kb + 3, lim));
                int s4 = __shfl(sidx, min(kb + 4, lim));
                int s5 = __shfl(sidx, min(kb + 5, lim));
                uint u0 = msg[(size_t)s0 * 64 + lane];
                uint u1 = msg[(size_t)s1 * 64 + lane];
                uint u2 = msg[(size_t)s2 * 64 + lane];
                uint u3 = msg[(size_t)s3 * 64 + lane];
                uint u4 = msg[(size_t)s4 * 64 + lane];
                uint u5 = msg[(size_t)s5 * 64 + lane];
                u1 = (kb + 1 < cnt) ? u1 : 0u;
                u2 = (kb + 2 < cnt) ? u2 : 0u;
                u3 = (kb + 3 < cnt) ? u3 : 0u;
                u4 = (kb + 4 < cnt) ? u4 : 0u;
                u5 = (kb + 5 < cnt) ? u5 : 0u;
                a0 = __hadd2(a0, u2h2(u0));
                a1 = __hadd2(a1, u2h2(u1));
                a2 = __hadd2(a2, u2h2(u2));
                a0 = __hadd2(a0, u2h2(u3));
                a1 = __hadd2(a1, u2h2(u4));
                a2 = __hadd2(a2, u2h2(u5));
            }
        }
        __half2 acc = __hadd2(__hadd2(a0, a1), a2);
        float2 f = __half22float2(acc);
        float dd = dinv[wid];
        float ax = fmaxf(f.x * dd + bx, 0.f);
        float ay = fmaxf(f.y * dd + by, 0.f);
        *(uint*)&ht[r * LP + lane * 2] = h22u(__floats2half2_rn(ax, ay));
    }
    __syncthreads();

    float4v acc = (float4v)0.f;
    const int arow = lane & 15;
    #pragma unroll
    for (int kk = 0; kk < 4; ++kk) {
        short8v a = *(const short8v*)&ht[arow * LP + kk * 32 + ((lane >> 4) * 8)];
        acc = __builtin_amdgcn_mfma_f32_16x16x32_f16(a, wf[(kk * 8 + w) * 64 + lane],
                                                     acc, 0, 0, 0);
    }
    const int orow = row0 + ((lane >> 4) << 2);
    #pragma unroll
    for (int r = 0; r < 4; ++r) {
        int row = orow + r;
        float dr = dinv[row];
        Y[(size_t)row * 128 + w * 16 + (lane & 15)] = f2h_u(acc[r] * dr);
    }
}

// ---------------- FUSED agg2 + pool: per-block (4 nodes) partial sums, A/B by graph ----------------

__global__ __launch_bounds__(256) void k_agg_pool(const uint* __restrict__ msg,
                                                  const float* __restrict__ dinv,
                                                  const int2* __restrict__ nr,
                                                  const int* __restrict__ csr,
                                                  const int* __restrict__ batch,
                                                  float* __restrict__ pA,
                                                  float* __restrict__ pB) {
    __shared__ float red[4][128];
    __shared__ int selw[4];
    const int blk = blockIdx.x;
    const int t = threadIdx.x;
    const int lane = t & 63;
    const int w = t >> 6;
    const int wid = blk * 4 + w;  // N % 4 == 0, always valid

    __half2 a0 = u2h2(msg[(size_t)wid * 64 + lane]);
    __half2 a1 = u2h2(0u), a2 = u2h2(0u);
    const int2 rg = nr[wid];
    const int e0 = rg.x, e1 = rg.y;
    for (int e = e0; e < e1; e += 64) {
        int me = e + lane;
        int sidx = (me < e1) ? csr[me] : 0;
        int cnt = min(64, e1 - e);
        for (int kb = 0; kb < cnt; kb += 6) {
            int lim = cnt - 1;
            int s0 = __shfl(sidx, min(kb + 0, lim));
            int s1 = __shfl(sidx, min(kb + 1, lim));
            int s2 = __shfl(sidx, min(kb + 2, lim));
            int s3 = __shfl(sidx, min(kb + 3, lim));
            int s4 = __shfl(sidx, min(kb + 4, lim));
            int s5 = __shfl(sidx, min(kb + 5, lim));
            uint u0 = msg[(size_t)s0 * 64 + lane];
            uint u1 = msg[(size_t)s1 * 64 + lane];
            uint u2 = msg[(size_t)s2 * 64 + lane];
            uint u3 = msg[(size_t)s3 * 64 + lane];
            uint u4 = msg[(size_t)s4 * 64 + lane];
            uint u5 = msg[(size_t)s5 * 64 + lane];
            u1 = (kb + 1 < cnt) ? u1 : 0u;
            u2 = (kb + 2 < cnt) ? u2 : 0u;
            u3 = (kb + 3 < cnt) ? u3 : 0u;
            u4 = (kb + 4 < cnt) ? u4 : 0u;
            u5 = (kb + 5 < cnt) ? u5 : 0u;
            a0 = __hadd2(a0, u2h2(u0));
            a1 = __hadd2(a1, u2h2(u1));
            a2 = __hadd2(a2, u2h2(u2));
            a0 = __hadd2(a0, u2h2(u3));
            a1 = __hadd2(a1, u2h2(u4));
            a2 = __hadd2(a2, u2h2(u5));
        }
    }
    __half2 acc = __hadd2(__hadd2(a0, a1), a2);
    float2 f = __half22float2(acc);
    float dd = dinv[wid];
    red[w][lane * 2] = f.x * dd;
    red[w][lane * 2 + 1] = f.y * dd;
    if (lane == 0) selw[w] = (batch[wid] != batch[blk * 4]) ? 1 : 0;
    __syncthreads();
    if (t < 128) {
        float a = 0.f, b = 0.f;
        #pragma unroll
        for (int ww = 0; ww < 4; ++ww) {
            float v = red[ww][t];
            if (selw[ww]) b += v; else a += v;
        }
        pA[(size_t)blk * 128 + t] = a;
        if (selw[0] | selw[1] | selw[2] | selw[3])
            pB[(size_t)blk * 128 + t] = b;
    }
}

// ---------------- final: per-graph reduce (512 threads, 4-way strided) + linear head ----------------

__global__ __launch_bounds__(512) void k_final(const float* __restrict__ pA,
                                               const float* __restrict__ pB,
                                               const int* __restrict__ batch,
                                               const int* __restrict__ gstart,
                                               const int* __restrict__ gend,
                                               const float* __restrict__ b2,
                                               const float* __restrict__ linW,
                                               const float* __restrict__ linb,
                                               float* __restrict__ out) {
    __shared__ float sq[4][128];
    __shared__ float red[128][8];
    int g = blockIdx.x;
    int t = threadIdx.x;
    int c = t & 127;   // channel
    int q = t >> 7;    // quarter 0..3
    int b0 = gstart[g] >> 2;
    int b1 = (gend[g] - 1) >> 2;
    float v = 0.f;
    #pragma unroll 4
    for (int b = b0 + 1 + q; b <= b1; b += 4)
        v += pA[(size_t)b * 128 + c];
    if (q == 0)
        v += ((batch[b0 * 4] != g) ? pB : pA)[(size_t)b0 * 128 + c];
    sq[q][c] = v;
    __syncthreads();
    if (t < 128) {
        float sv = sq[0][t] + sq[1][t] + sq[2][t] + sq[3][t];
        float cnt = (float)(gend[g] - gstart[g]);
        sv = sv / fmaxf(cnt, 1.0f) + b2[t];
        #pragma unroll
        for (int k = 0; k < 8; ++k) red[t][k] = sv * linW[(size_t)t * 8 + k];
    }
    __syncthreads();
    #pragma unroll
    for (int st = 64; st > 0; st >>= 1) {
        if (t < st) {
            #pragma unroll
            for (int k = 0; k < 8; ++k) red[t][k] += red[t + st][k];
        }
        __syncthreads();
    }
    if (t < 8) out[(size_t)g * 8 + t] = red[0][t] + linb[t];
}

// ---------------- launch ----------------

extern "C" void kernel_launch(void* const* d_in, const int* in_sizes, int n_in,
                              void* d_out, int out_size, void* d_ws, size_t ws_size,
                              hipStream_t stream) {
    const float* x     = (const float*)d_in[0];
    const int*   ei    = (const int*)d_in[1];  // [2,E]: src = ei, dst = ei+E
    const int*   batch = (const int*)d_in[2];
    const float* W1    = (const float*)d_in[3];
    const float* b1    = (const float*)d_in[4];
    const float* W2    = (const float*)d_in[5];
    const float* b2    = (const float*)d_in[6];
    const float* linW  = (const float*)d_in[7];
    const float* linb  = (const float*)d_in[8];
    float* out = (float*)d_out;

    const int N = NNODES, E = NEDGES;
    const int* src = ei;
    const int* dst = ei + E;

    char* ws = (char*)d_ws;
    uint*  bufA16 = (uint*)ws;     ws += (size_t)N * 64 * 4;   // msg1 (fp16), 25.6MB
    uint*  bufH16 = (uint*)ws;     ws += (size_t)N * 64 * 4;   // msg2 (fp16), 25.6MB
    float* dinv   = (float*)ws;    ws += (size_t)N * 4;
    int2*  nr     = (int2*)ws;     ws += (size_t)N * 8;        // per-node (start,end)
    int*   csr    = (int*)ws;      ws += (size_t)NB * CAP * 4; // 12.8MB bucket frames
    int*   bcur   = (int*)ws;      ws += NB * 4;               // zero region
    int*   gstart = (int*)ws;      ws += NGRAPHS * 4;
    int*   gend   = (int*)ws;      ws += NGRAPHS * 4;
    short8v* wf1  = (short8v*)ws;  ws += 2048 * 16;            // fragment-ordered W1 (32KB)
    short8v* wf2  = (short8v*)ws;  ws += 2048 * 16;            // fragment-ordered W2 (32KB)
    float* pA     = (float*)ws;    ws += (size_t)NAB * 128 * 4;  // 12.8MB
    float* pB     = (float*)ws;    ws += (size_t)NAB * 128 * 4;  // 12.8MB
    // pairs aliases bufH16 (12.8MB < 25.6MB): CSR build completes before msg2 written
    uint*  pairs  = (uint*)bufH16;

    const int B = 256;

    // setup: zero(4) + prepw(2) + bounds(391) = 397 blocks
    k_setup<<<397, B, 0, stream>>>(bcur, W1, W2, wf1, wf2, batch, gstart, gend);

    // CSR build
    k_bscatter<<<(E + 8191) / 8192, 512, 0, stream>>>(src, dst, bcur, pairs, E);
    k_build<<<NB, 512, 0, stream>>>(pairs, bcur, nr, dinv, csr, N);

    // layer 1 GEMM: msg1 = (x @ W1) * dinv  (16 rows/block, LDS-staged)
    k_gemm_f32<<<N / 16, B, 0, stream>>>((const float4*)x, wf1, dinv, (ushort*)bufA16, N);

    // fused agg1 + GEMM2: msg2 = (relu(agg(msg1)+b1) @ W2) * dinv  (8 waves, 2 nodes/wave)
    k_agg_gemm<<<N / 16, 512, 0, stream>>>(bufA16, dinv, nr, csr, b1, wf2,
                                           (ushort*)bufH16, N);

    // fused agg2 + pool: per-block partial sums of h2
    k_agg_pool<<<NAB, B, 0, stream>>>(bufH16, dinv, nr, csr, batch, pA, pB);

    // per-graph reduce + head
    k_final<<<NGRAPHS, 512, 0, stream>>>(pA, pB, batch, gstart, gend, b2, linW, linb, out);
}

// Round 23
// 167.833 us; speedup vs baseline: 2.0082x; 1.1602x over previous
//
#include <hip/hip_runtime.h>
#include <hip/hip_fp16.h>
#include <cstdint>
#include <cstddef>

#define NNODES 100000
#define NEDGES 1600000
#define NGRAPHS 64
#define BSHIFT 7
#define BRANGE 128
#define NB 782   // ceil(NNODES / 128)
#define CAP 4096 // edges per bucket frame (padded sum < 3100 at 25 sigma)
#define NZ NB    // ints to zero (bcur)
#define LP 136   // LDS row pitch in shorts (272B)
#define NAB 25000 // agg2/pool blocks (N/4)

typedef short short8v __attribute__((ext_vector_type(8)));
typedef float float4v __attribute__((ext_vector_type(4)));
typedef float float2v __attribute__((ext_vector_type(2)));

__device__ inline short f2h_s(float f) {
    __half h = __float2half(f);
    return __builtin_bit_cast(short, h);
}
__device__ inline ushort f2h_u(float f) {
    __half h = __float2half(f);
    return __builtin_bit_cast(ushort, h);
}
__device__ inline uint h22u(__half2 h) { return __builtin_bit_cast(uint, h); }

// fp8 e4m3 (OCP) pack/unpack via HW cvt
__device__ inline float2v fp8x2_f32(uint u) {
    return __builtin_amdgcn_cvt_pk_f32_fp8((int)u, false);
}
__device__ inline ushort f32_fp8x2(float a, float b) {
    return (ushort)__builtin_amdgcn_cvt_pk_fp8_f32(a, b, 0, false);
}

// ---------------- setup: zero ∪ prepw ∪ zero-sentinel-rows ∪ bounds ----------------

__global__ __launch_bounds__(256) void k_setup(int* __restrict__ zb,
                                               const float* __restrict__ W1,
                                               const float* __restrict__ W2,
                                               short8v* __restrict__ o1,
                                               short8v* __restrict__ o2,
                                               uint* __restrict__ rowNA,
                                               uint* __restrict__ rowNH,
                                               const int* __restrict__ batch,
                                               int* __restrict__ gstart,
                                               int* __restrict__ gend) {
    int b = blockIdx.x, t = threadIdx.x;
    if (b < 4) {
        int i = b * 256 + t;
        if (i < NZ) zb[i] = 0;
    } else if (b < 6) {
        const float* W = (b == 5) ? W2 : W1;
        short8v* o = (b == 5) ? o2 : o1;
        for (int s = t; s < 2048; s += 256) {
            int p = s >> 6, l = s & 63;
            int kb = (p >> 3) * 32 + ((l >> 4) * 8);
            int j = (p & 7) * 16 + (l & 15);
            short8v v;
            #pragma unroll
            for (int i = 0; i < 8; ++i)
                v[i] = f2h_s(W[(size_t)(kb + i) * 128 + j]);
            o[s] = v;
        }
    } else if (b == 6) {
        if (t < 32) rowNA[t] = 0u;          // fp8 zero row for msg1 (128B)
        else if (t < 64) rowNH[t - 32] = 0u; // fp8 zero row for msg2
    } else {
        int i = (b - 7) * 256 + t;
        if (i < NNODES) {
            int bb = batch[i];
            if (i == 0 || batch[i - 1] != bb) gstart[bb] = i;
            if (i == NNODES - 1 || batch[i + 1] != bb) gend[bb] = i + 1;
        }
    }
}

// ---------------- P1: bucket scatter, 512 thr x 8192 edges/block ----------------

#define P1_EPT 16
__global__ __launch_bounds__(512) void k_bscatter(const int* __restrict__ src,
                                                  const int* __restrict__ dst,
                                                  int* __restrict__ bcur,
                                                  uint* __restrict__ pairs, int E) {
    __shared__ int h[NB];
    __shared__ int base[NB];
    int t = threadIdx.x;
    long long c0 = (long long)blockIdx.x * 8192;
    if (c0 >= E) return;
    for (int i = t; i < NB; i += 512) h[i] = 0;
    __syncthreads();
    int myb[P1_EPT], mylp[P1_EPT];
    uint myv[P1_EPT];
    #pragma unroll
    for (int k = 0; k < P1_EPT; ++k) {
        long long e = c0 + t + k * 512;
        if (e < E) {
            int d = dst[e];
            myv[k] = (uint)src[e] | ((uint)(d & (BRANGE - 1)) << 24);
            myb[k] = d >> BSHIFT;
            mylp[k] = atomicAdd(&h[myb[k]], 1);
        } else myb[k] = -1;
    }
    __syncthreads();
    for (int i = t; i < NB; i += 512)
        base[i] = h[i] ? atomicAdd(&bcur[i], h[i]) : 0;
    __syncthreads();
    #pragma unroll
    for (int k = 0; k < P1_EPT; ++k)
        if (myb[k] >= 0) {
            int pos = base[myb[k]] + mylp[k];
            if (pos < CAP)
                pairs[(size_t)myb[k] * CAP + pos] = myv[k];
        }
}

// ---------------- fused per-bucket: hist -> dinv + PADDED ranges -> CSR + sentinels ----------------

__global__ __launch_bounds__(512) void k_build(const uint* __restrict__ pairs,
                                               const int* __restrict__ bcur,
                                               int2* __restrict__ nr,
                                               float* __restrict__ dinv,
                                               int* __restrict__ csr, int N) {
    __shared__ int h[256];
    __shared__ int sh[256];
    __shared__ int cur[BRANGE];
    __shared__ int pend[BRANGE];
    int b = blockIdx.x, t = threadIdx.x;
    if (t < 256) h[t] = 0;
    __syncthreads();
    const int p0 = b * CAP;
    const int cntb = min(bcur[b], CAP);
    for (int p = t; p < cntb; p += 512)
        atomicAdd(&h[pairs[p0 + p] >> 24], 1);
    __syncthreads();
    int myh = (t < 256) ? h[t] : 0;
    int p8 = (myh + 7) & ~7;   // pad node range to multiple of 8
    if (t < 256) sh[t] = p8;
    __syncthreads();
    #pragma unroll
    for (int d = 1; d < 256; d <<= 1) {
        int val = (t >= d && t < 256) ? sh[t - d] : 0;
        __syncthreads();
        if (t < 256) sh[t] += val;
        __syncthreads();
    }
    int node = (b << BSHIFT) + t;
    if (t < BRANGE) {
        int st = p0 + sh[t] - p8;
        cur[t] = st;
        pend[t] = st + p8;
        if (node < N) {
            nr[node] = make_int2(st, st + p8);
            dinv[node] = rsqrtf((float)(myh + 1));
        }
    }
    __syncthreads();
    for (int p = t; p < cntb; p += 512) {
        uint pr = pairs[p0 + p];
        int pos = atomicAdd(&cur[pr >> 24], 1);
        csr[pos] = (int)(pr & 0x00FFFFFFu);
    }
    __syncthreads();
    if (t < BRANGE) {
        for (int pos = cur[t]; pos < pend[t]; ++pos)
            csr[pos] = N;   // sentinel -> zero msg row
    }
}

// ---------------- GEMM1: 16 rows/block, LDS staging, column-split MFMA, fp8 out ----------------

__global__ __launch_bounds__(256) void k_gemm_f32(const float4* __restrict__ X4,
                                                  const short8v* __restrict__ wf,
                                                  const float* __restrict__ dinv,
                                                  ushort* __restrict__ Y8, int n) {
    __shared__ ushort ht[16 * LP];
    const int t = threadIdx.x;
    const int lane = t & 63;
    const int w = t >> 6;
    const int row0 = blockIdx.x * 16;

    #pragma unroll
    for (int s = t; s < 16 * 32; s += 256) {
        int row = s >> 5, q = s & 31;
        float4 v = X4[(size_t)(row0 + row) * 32 + q];
        ushort2 h0 = make_ushort2(f2h_u(v.x), f2h_u(v.y));
        ushort2 h1 = make_ushort2(f2h_u(v.z), f2h_u(v.w));
        *(ushort2*)&ht[row * LP + q * 4] = h0;
        *(ushort2*)&ht[row * LP + q * 4 + 2] = h1;
    }
    __syncthreads();

    float4v acc[2];
    acc[0] = (float4v)0.f;
    acc[1] = (float4v)0.f;
    const int arow = lane & 15;
    const int ct0 = w * 2;
    #pragma unroll
    for (int kk = 0; kk < 4; ++kk) {
        short8v a = *(const short8v*)&ht[arow * LP + kk * 32 + ((lane >> 4) * 8)];
        acc[0] = __builtin_amdgcn_mfma_f32_16x16x32_f16(a, wf[(kk * 8 + ct0) * 64 + lane],
                                                        acc[0], 0, 0, 0);
        acc[1] = __builtin_amdgcn_mfma_f32_16x16x32_f16(a, wf[(kk * 8 + ct0 + 1) * 64 + lane],
                                                        acc[1], 0, 0, 0);
    }
    const int orow = row0 + ((lane >> 4) << 2);
    #pragma unroll
    for (int r = 0; r < 4; ++r) {
        int row = orow + r;
        float dr = dinv[row];
        #pragma unroll
        for (int j = 0; j < 2; ++j) {
            float a = acc[j][r] * dr;
            float b = __shfl_xor(a, 1);
            if (!(lane & 1))
                Y8[(size_t)row * 64 + (ct0 + j) * 8 + ((lane & 15) >> 1)] = f32_fp8x2(a, b);
        }
    }
}

// ---------------- shared agg body: fp8 gathers, 8-deep, no masks (padded CSR) ----------------

__device__ inline void agg_node(const ushort* __restrict__ msg,
                                const int* __restrict__ csr,
                                int e0, int e1, int lane, uint uself,
                                float& outx, float& outy) {
    float2v fs = fp8x2_f32(uself);
    float ax0 = fs[0], ay0 = fs[1];
    float ax1 = 0.f, ay1 = 0.f, ax2 = 0.f, ay2 = 0.f, ax3 = 0.f, ay3 = 0.f;
    for (int e = e0; e < e1; e += 64) {
        int me = e + lane;
        int sidx = (me < e1) ? csr[me] : NNODES;
        int cnt = min(64, e1 - e);   // multiple of 8
        for (int kb = 0; kb < cnt; kb += 8) {
            int s0 = __shfl(sidx, kb + 0);
            int s1 = __shfl(sidx, kb + 1);
            int s2 = __shfl(sidx, kb + 2);
            int s3 = __shfl(sidx, kb + 3);
            int s4 = __shfl(sidx, kb + 4);
            int s5 = __shfl(sidx, kb + 5);
            int s6 = __shfl(sidx, kb + 6);
            int s7 = __shfl(sidx, kb + 7);
            uint u0 = msg[(size_t)s0 * 64 + lane];
            uint u1 = msg[(size_t)s1 * 64 + lane];
            uint u2 = msg[(size_t)s2 * 64 + lane];
            uint u3 = msg[(size_t)s3 * 64 + lane];
            uint u4 = msg[(size_t)s4 * 64 + lane];
            uint u5 = msg[(size_t)s5 * 64 + lane];
            uint u6 = msg[(size_t)s6 * 64 + lane];
            uint u7 = msg[(size_t)s7 * 64 + lane];
            float2v f0 = fp8x2_f32(u0);
            float2v f1 = fp8x2_f32(u1);
            float2v f2 = fp8x2_f32(u2);
            float2v f3 = fp8x2_f32(u3);
            float2v f4 = fp8x2_f32(u4);
            float2v f5 = fp8x2_f32(u5);
            float2v f6 = fp8x2_f32(u6);
            float2v f7 = fp8x2_f32(u7);
            ax0 += f0[0]; ay0 += f0[1];
            ax1 += f1[0]; ay1 += f1[1];
            ax2 += f2[0]; ay2 += f2[1];
            ax3 += f3[0]; ay3 += f3[1];
            ax0 += f4[0]; ay0 += f4[1];
            ax1 += f5[0]; ay1 += f5[1];
            ax2 += f6[0]; ay2 += f6[1];
            ax3 += f7[0]; ay3 += f7[1];
        }
    }
    outx = (ax0 + ax1) + (ax2 + ax3);
    outy = (ay0 + ay1) + (ay2 + ay3);
}

// ---------------- FUSED agg1 + GEMM2: 8 waves, 2 nodes/wave, 1 col-tile/wave, fp8 I/O ----------------

__global__ __launch_bounds__(512) void k_agg_gemm(const ushort* __restrict__ msg,
                                                  const float* __restrict__ dinv,
                                                  const int2* __restrict__ nr,
                                                  const int* __restrict__ csr,
                                                  const float* __restrict__ bias,
                                                  const short8v* __restrict__ wf,
                                                  ushort* __restrict__ Y8, int n) {
    __shared__ ushort ht[16 * LP];
    const int t = threadIdx.x;
    const int lane = t & 63;
    const int w = t >> 6;           // 0..7
    const int row0 = blockIdx.x * 16;
    const float bx = bias[lane * 2];
    const float by = bias[lane * 2 + 1];

    #pragma unroll
    for (int i = 0; i < 2; ++i) {
        const int r = w * 2 + i;
        const int wid = row0 + r;
        const int2 rg = nr[wid];
        uint uself = msg[(size_t)wid * 64 + lane];
        float sx, sy;
        agg_node(msg, csr, rg.x, rg.y, lane, uself, sx, sy);
        float dd = dinv[wid];
        float ax = fmaxf(sx * dd + bx, 0.f);
        float ay = fmaxf(sy * dd + by, 0.f);
        *(uint*)&ht[r * LP + lane * 2] = h22u(__floats2half2_rn(ax, ay));
    }
    __syncthreads();

    float4v acc = (float4v)0.f;
    const int arow = lane & 15;
    #pragma unroll
    for (int kk = 0; kk < 4; ++kk) {
        short8v a = *(const short8v*)&ht[arow * LP + kk * 32 + ((lane >> 4) * 8)];
        acc = __builtin_amdgcn_mfma_f32_16x16x32_f16(a, wf[(kk * 8 + w) * 64 + lane],
                                                     acc, 0, 0, 0);
    }
    const int orow = row0 + ((lane >> 4) << 2);
    #pragma unroll
    for (int r = 0; r < 4; ++r) {
        int row = orow + r;
        float dr = dinv[row];
        float a = acc[r] * dr;
        float b = __shfl_xor(a, 1);
        if (!(lane & 1))
            Y8[(size_t)row * 64 + w * 8 + ((lane & 15) >> 1)] = f32_fp8x2(a, b);
    }
}

// ---------------- FUSED agg2 + pool: fp8 gathers, per-block partials, A/B by graph ----------------

__global__ __launch_bounds__(256) void k_agg_pool(const ushort* __restrict__ msg,
                                                  const float* __restrict__ dinv,
                                                  const int2* __restrict__ nr,
                                                  const int* __restrict__ csr,
                                                  const int* __restrict__ batch,
                                                  float* __restrict__ pA,
                                                  float* __restrict__ pB) {
    __shared__ float red[4][128];
    __shared__ int selw[4];
    const int blk = blockIdx.x;
    const int t = threadIdx.x;
    const int lane = t & 63;
    const int w = t >> 6;
    const int wid = blk * 4 + w;

    const int2 rg = nr[wid];
    uint uself = msg[(size_t)wid * 64 + lane];
    float sx, sy;
    agg_node(msg, csr, rg.x, rg.y, lane, uself, sx, sy);
    float dd = dinv[wid];
    red[w][lane * 2] = sx * dd;
    red[w][lane * 2 + 1] = sy * dd;
    if (lane == 0) selw[w] = (batch[wid] != batch[blk * 4]) ? 1 : 0;
    __syncthreads();
    if (t < 128) {
        float a = 0.f, b = 0.f;
        #pragma unroll
        for (int ww = 0; ww < 4; ++ww) {
            float v = red[ww][t];
            if (selw[ww]) b += v; else a += v;
        }
        pA[(size_t)blk * 128 + t] = a;
        if (selw[0] | selw[1] | selw[2] | selw[3])
            pB[(size_t)blk * 128 + t] = b;
    }
}

// ---------------- final: per-graph reduce + linear head ----------------

__global__ __launch_bounds__(512) void k_final(const float* __restrict__ pA,
                                               const float* __restrict__ pB,
                                               const int* __restrict__ batch,
                                               const int* __restrict__ gstart,
                                               const int* __restrict__ gend,
                                               const float* __restrict__ b2,
                                               const float* __restrict__ linW,
                                               const float* __restrict__ linb,
                                               float* __restrict__ out) {
    __shared__ float sq[4][128];
    __shared__ float red[128][8];
    int g = blockIdx.x;
    int t = threadIdx.x;
    int c = t & 127;
    int q = t >> 7;
    int b0 = gstart[g] >> 2;
    int b1 = (gend[g] - 1) >> 2;
    float v = 0.f;
    #pragma unroll 4
    for (int b = b0 + 1 + q; b <= b1; b += 4)
        v += pA[(size_t)b * 128 + c];
    if (q == 0)
        v += ((batch[b0 * 4] != g) ? pB : pA)[(size_t)b0 * 128 + c];
    sq[q][c] = v;
    __syncthreads();
    if (t < 128) {
        float sv = sq[0][t] + sq[1][t] + sq[2][t] + sq[3][t];
        float cnt = (float)(gend[g] - gstart[g]);
        sv = sv / fmaxf(cnt, 1.0f) + b2[t];
        #pragma unroll
        for (int k = 0; k < 8; ++k) red[t][k] = sv * linW[(size_t)t * 8 + k];
    }
    __syncthreads();
    #pragma unroll
    for (int st = 64; st > 0; st >>= 1) {
        if (t < st) {
            #pragma unroll
            for (int k = 0; k < 8; ++k) red[t][k] += red[t + st][k];
        }
        __syncthreads();
    }
    if (t < 8) out[(size_t)g * 8 + t] = red[0][t] + linb[t];
}

// ---------------- launch ----------------

extern "C" void kernel_launch(void* const* d_in, const int* in_sizes, int n_in,
                              void* d_out, int out_size, void* d_ws, size_t ws_size,
                              hipStream_t stream) {
    const float* x     = (const float*)d_in[0];
    const int*   ei    = (const int*)d_in[1];
    const int*   batch = (const int*)d_in[2];
    const float* W1    = (const float*)d_in[3];
    const float* b1    = (const float*)d_in[4];
    const float* W2    = (const float*)d_in[5];
    const float* b2    = (const float*)d_in[6];
    const float* linW  = (const float*)d_in[7];
    const float* linb  = (const float*)d_in[8];
    float* out = (float*)d_out;

    const int N = NNODES, E = NEDGES;
    const int* src = ei;
    const int* dst = ei + E;

    char* ws = (char*)d_ws;
    ushort* msgA8 = (ushort*)ws;   ws += (size_t)(N + 1) * 128;  // msg1 fp8 + zero row, 12.8MB
    ushort* msgH8 = (ushort*)ws;   ws += (size_t)(N + 1) * 128;  // msg2 fp8 + zero row
    float* dinv   = (float*)ws;    ws += (size_t)N * 4;
    int2*  nr     = (int2*)ws;     ws += (size_t)N * 8;
    int*   csr    = (int*)ws;      ws += (size_t)NB * CAP * 4;   // 12.8MB
    uint*  pairs  = (uint*)ws;     ws += (size_t)NB * CAP * 4;   // 12.8MB (de-aliased)
    int*   bcur   = (int*)ws;      ws += NB * 4;                 // zero region
    int*   gstart = (int*)ws;      ws += NGRAPHS * 4;
    int*   gend   = (int*)ws;      ws += NGRAPHS * 4;
    short8v* wf1  = (short8v*)ws;  ws += 2048 * 16;
    short8v* wf2  = (short8v*)ws;  ws += 2048 * 16;
    float* pA     = (float*)ws;    ws += (size_t)NAB * 128 * 4;
    float* pB     = (float*)ws;    ws += (size_t)NAB * 128 * 4;

    const int B = 256;

    // setup: zero(4) + prepw(2) + zero-rows(1) + bounds(391) = 398 blocks
    k_setup<<<398, B, 0, stream>>>(bcur, W1, W2, wf1, wf2,
                                   (uint*)(msgA8 + (size_t)N * 64),
                                   (uint*)(msgH8 + (size_t)N * 64),
                                   batch, gstart, gend);

    // CSR build (padded ranges + sentinels)
    k_bscatter<<<(E + 8191) / 8192, 512, 0, stream>>>(src, dst, bcur, pairs, E);
    k_build<<<NB, 512, 0, stream>>>(pairs, bcur, nr, dinv, csr, N);

    // layer 1 GEMM: msg1 = (x @ W1) * dinv  -> fp8
    k_gemm_f32<<<N / 16, B, 0, stream>>>((const float4*)x, wf1, dinv, msgA8, N);

    // fused agg1 + GEMM2: msg2 = (relu(agg(msg1)+b1) @ W2) * dinv -> fp8
    k_agg_gemm<<<N / 16, 512, 0, stream>>>(msgA8, dinv, nr, csr, b1, wf2, msgH8, N);

    // fused agg2 + pool
    k_agg_pool<<<NAB, B, 0, stream>>>(msgH8, dinv, nr, csr, batch, pA, pB);

    // per-graph reduce + head
    k_final<<<NGRAPHS, 512, 0, stream>>>(pA, pB, batch, gstart, gend, b2, linW, linb, out);
}